// Round 6
// baseline (2096.958 us; speedup 1.0000x reference)
//
#include <hip/hip_runtime.h>
#include <hip/hip_bf16.h>
#include <math.h>

// ChunkedLinearCrossEntropyLoss fused kernel for MI355X (gfx950) — R6
//
// hidden[4096,2048] f32, weight[32768,2048] f32, targets[4096] i32 -> scalar
//
//  Kc  convert_fp8  : f32 -> fp8 e4m3 copies, K-order pre-permuted so one
//                     ds_read_b128 yields both K-half MFMA fragments
//  K0  target_logit : x_t[row] = softcap(h[row].w[tgt[row]]) fp32 (exact)
//  K1  gemm_fp8     : 256x256 tile, BK=64, 8 waves, 2 windows/tile deep
//                     pipeline (vmcnt(4), T2-style swizzle, setprio).
//                     fp8 halves LDS bytes -> MFMA-bound; LDS 66KB -> 2 blk/CU
//  K2  row_reduce   : sum column-block partials per row
//  K3  final_reduce : scalar loss
//
// fp8 buffer layout: row-major [row][2048 B]; within each 64-byte K-window t
// byte b holds original k = t*64 + ((b>>3)&1)*32 + ((b>>4)&3)*8 + (b&7).
// So 16B slot g of window t = fragment pair (kk=0, kk=1) for lane-group g.

#define N_ROWS 4096
#define DIM    2048
#define VOCAB  32768
#define IGNORE_IDX (-100)

#define BM 256
#define BN 256
#define BK 64
#define NT (DIM / BK)            // 32 K-tiles
#define NCB (VOCAB / BN)         // 128 column blocks
#define ROW_TILES (N_ROWS / BM)  // 16

typedef short s16x8 __attribute__((ext_vector_type(8)));
typedef unsigned short u16x8 __attribute__((ext_vector_type(8)));
typedef float f32x4 __attribute__((ext_vector_type(4)));
typedef long  l64x2 __attribute__((ext_vector_type(2)));

#define AS3(p) ((__attribute__((address_space(3))) void*)(p))
#define AS1(p) ((const __attribute__((address_space(1))) void*)(p))

// 20*tanh(x/20) via hardware exp; clamp keeps exp finite for any input.
__device__ __forceinline__ float softcap(float x) {
    x = fminf(80.f, fmaxf(-80.f, x));
    float e = __expf(x * 0.1f);
    return 20.f * (e - 1.f) * __builtin_amdgcn_rcpf(e + 1.f);
}

// f32 -> bf16 RNE (fallback path only)
__device__ __forceinline__ unsigned short f2bf(float f) {
    union { float f; unsigned u; } v; v.f = f;
    unsigned r = v.u + 0x7FFFu + ((v.u >> 16) & 1u);
    return (unsigned short)(r >> 16);
}

// ---------------------------------------------------------------------------
// Kc: f32 -> fp8 e4m3 with the fragment K-permutation baked in.
// Thread handles (row, window t, group g): writes 16 B at row*2048+t*64+g*16
// containing k = t*64+g*8+[0,8) then k = t*64+32+g*8+[0,8).
// ---------------------------------------------------------------------------
__global__ __launch_bounds__(256) void convert_fp8(
    const float* __restrict__ src, unsigned char* __restrict__ dst, int nchunk)
{
    int idx = blockIdx.x * 256 + threadIdx.x;
    int stride = gridDim.x * 256;
    for (int i = idx; i < nchunk; i += stride) {
        int row = i >> 7;
        int c   = i & 127;
        int t   = c >> 2;
        int g   = c & 3;
        const float* p = src + (size_t)row * DIM + t * 64 + g * 8;
        float4 a0 = *(const float4*)(p);
        float4 a1 = *(const float4*)(p + 4);
        float4 b0 = *(const float4*)(p + 32);
        float4 b1 = *(const float4*)(p + 36);
        int w0 = __builtin_amdgcn_cvt_pk_fp8_f32(a0.x, a0.y, 0, false);
        w0     = __builtin_amdgcn_cvt_pk_fp8_f32(a0.z, a0.w, w0, true);
        int w1 = __builtin_amdgcn_cvt_pk_fp8_f32(a1.x, a1.y, 0, false);
        w1     = __builtin_amdgcn_cvt_pk_fp8_f32(a1.z, a1.w, w1, true);
        int w2 = __builtin_amdgcn_cvt_pk_fp8_f32(b0.x, b0.y, 0, false);
        w2     = __builtin_amdgcn_cvt_pk_fp8_f32(b0.z, b0.w, w2, true);
        int w3 = __builtin_amdgcn_cvt_pk_fp8_f32(b1.x, b1.y, 0, false);
        w3     = __builtin_amdgcn_cvt_pk_fp8_f32(b1.z, b1.w, w3, true);
        *(int4*)(dst + (size_t)row * DIM + t * 64 + g * 16) =
            make_int4(w0, w1, w2, w3);
    }
}

// ---------------------------------------------------------------------------
// K0: x_t[row] = softcap(dot(hidden[row], weight[tgt])) fp32. 1 wave/row.
// ---------------------------------------------------------------------------
__global__ __launch_bounds__(256) void target_logit(
    const float* __restrict__ hidden, const float* __restrict__ weight,
    const int* __restrict__ targets, float* __restrict__ xtbuf)
{
    int row  = blockIdx.x * 4 + (threadIdx.x >> 6);
    int lane = threadIdx.x & 63;
    if (row >= N_ROWS) return;
    int tgt = targets[row];
    if (tgt < 0 || tgt >= VOCAB) {
        if (lane == 0) xtbuf[row] = 0.f;
        return;
    }
    const float4* h4 = (const float4*)(hidden + (size_t)row * DIM);
    const float4* w4 = (const float4*)(weight + (size_t)tgt * DIM);
    float d = 0.f;
#pragma unroll
    for (int j = 0; j < DIM / 4 / 64; j++) {
        float4 a = h4[lane + 64 * j];
        float4 b = w4[lane + 64 * j];
        d += a.x * b.x + a.y * b.y + a.z * b.z + a.w * b.w;
    }
#pragma unroll
    for (int off = 1; off < 64; off <<= 1) d += __shfl_xor(d, off, 64);
    if (lane == 0) xtbuf[row] = softcap(d);
}

// ---------------------------------------------------------------------------
// K1: 256x256 8-wave fp8 GEMM, 2 windows/tile, fused row partials.
//
// LDS (66.5 KB): Abuf[2] @ {0,16K}, Bbuf[2] @ {32K,48K}, dummy @64K.
// Tile t reads buf t&1. Rows are 64 B; phys slot s_p holds logical slot
// s_p ^ (row&3)  (bank swizzle; readers XOR, stager inverse-permutes the
// global SOURCE and writes LDS linearly — rule both-sides-or-neither).
//
// Chunks (8 KB = 1 global_load_lds per wave, 16 rows/instr):
//   B0=B rows[0,128); B1=B rows[128,256);
//   A0=A rows[0,64)u[128,192); A1=A rows[64,128)u[192,256).
// tile t W0 (acc[0..3], A rows wr*128+[0,64)): read 4 B-frag + 4 A-frag
//   b128 pairs; stage (t+1,A1)->other buf; 32 MFMA; vmcnt(4); barrier.
// tile t W1 (acc[4..7]): read 4 A-frag pairs; stage (t+2,{B0,B1,A0})->this
//   buf (reads retired in W0); 32 MFMA; vmcnt(4); barrier.
// FIFO: steady 4 outstanding after each wait; confirmed chunks were issued
// >=2 windows earlier. ct>=NT chunks land in dummy (counts stay exact).
// ---------------------------------------------------------------------------
__device__ __forceinline__ void stage_chunk8(
    int kind, int ct, const unsigned char* Asrc, const unsigned char* Bsrc,
    unsigned char* smem, int w, int laneoff)
{
    // kind: 0=B0, 1=B1, 2=A0, 3=A1
    const int kcol = (ct & (NT - 1)) * 64;
    const int b = ct & 1;
    const int dum = (ct >= NT);
    const unsigned char* src;
    int base, row0;
    if (kind <= 1) {
        src = Bsrc; base = 32768 + b * 16384;
        row0 = kind * 128 + 16 * w;
    } else {
        src = Asrc; base = b * 16384;
        row0 = 16 * w + ((w >= 4) ? 64 : 0) + ((kind == 3) ? 64 : 0);
    }
    int l0 = dum ? 65536 : base + row0 * 64;
    __builtin_amdgcn_global_load_lds(
        AS1(src + (size_t)row0 * DIM + kcol + laneoff), AS3(smem + l0), 16, 0, 0);
}

__global__ __launch_bounds__(512, 4) void gemm_fp8(
    const unsigned char* __restrict__ A, const unsigned char* __restrict__ B,
    float2* __restrict__ part)
{
    __shared__ unsigned char smem[65536 + 1024] __attribute__((aligned(16)));

    const int bid  = blockIdx.x;
    const int brow = bid & (ROW_TILES - 1);   // 16 consecutive blocks share B panel
    const int bcol = bid >> 4;
    const int t0   = threadIdx.x;
    const int lane = t0 & 63;
    const int w    = t0 >> 6;                 // 0..7
    const int wr   = w >> 2;                  // 0..1 (M)
    const int wc   = w & 3;                   // 0..3 (N)
    const int li   = lane & 15;
    const int g    = lane >> 4;               // 0..3

    // fragment read: row ≡ li (mod 4); phys slot = g ^ (row&3); 16 B covers
    // both kk fragments thanks to the pre-permuted K order.
    const int colx = ((g ^ (lane & 3)) << 4);

    // staging source (inverse swizzle): lane l covers row_local l>>2,
    // phys slot l&3 -> logical slot (l&3)^((l>>2)&3).
    const int laneoff = (lane >> 2) * DIM + (((lane & 3) ^ ((lane >> 2) & 3)) << 4);

    const unsigned char* Asrc = A + (size_t)brow * BM * DIM;
    const unsigned char* Bsrc = B + (size_t)bcol * BN * DIM;

    f32x4 acc[8][4];
#pragma unroll
    for (int m = 0; m < 8; m++)
#pragma unroll
        for (int n = 0; n < 4; n++) acc[m][n] = (f32x4){0.f, 0.f, 0.f, 0.f};

    // ---- prologue: 7 chunks; vmcnt(4) confirms (0,B0),(0,B1),(0,A0) ----
    stage_chunk8(0, 0, Asrc, Bsrc, smem, w, laneoff);
    stage_chunk8(1, 0, Asrc, Bsrc, smem, w, laneoff);
    stage_chunk8(2, 0, Asrc, Bsrc, smem, w, laneoff);
    stage_chunk8(3, 0, Asrc, Bsrc, smem, w, laneoff);
    stage_chunk8(0, 1, Asrc, Bsrc, smem, w, laneoff);
    stage_chunk8(1, 1, Asrc, Bsrc, smem, w, laneoff);
    stage_chunk8(2, 1, Asrc, Bsrc, smem, w, laneoff);
    asm volatile("s_waitcnt vmcnt(4)" ::: "memory");
    __builtin_amdgcn_s_barrier();
    __builtin_amdgcn_sched_barrier(0);

    l64x2 bfr[4];

    for (int t = 0; t < NT; ++t) {
        const int b = t & 1;
        unsigned char* A_rd = smem + b * 16384;
        unsigned char* B_rd = smem + 32768 + b * 16384;

        // ---------------- window 0: acc[0..3] ----------------
        {
            l64x2 afr[4];
#pragma unroll
            for (int n = 0; n < 4; n++)
                bfr[n] = *(const l64x2*)(B_rd + (wc * 64 + n * 16 + li) * 64 + colx);
#pragma unroll
            for (int m = 0; m < 4; m++)
                afr[m] = *(const l64x2*)(A_rd + (wr * 128 + m * 16 + li) * 64 + colx);
            stage_chunk8(3, t + 1, Asrc, Bsrc, smem, w, laneoff);  // (t+1,A1)
            __builtin_amdgcn_s_setprio(1);
#pragma unroll
            for (int m = 0; m < 4; m++)
#pragma unroll
                for (int n = 0; n < 4; n++) {
                    acc[m][n] = __builtin_amdgcn_mfma_f32_16x16x32_fp8_fp8(
                        afr[m].x, bfr[n].x, acc[m][n], 0, 0, 0);
                    acc[m][n] = __builtin_amdgcn_mfma_f32_16x16x32_fp8_fp8(
                        afr[m].y, bfr[n].y, acc[m][n], 0, 0, 0);
                }
            __builtin_amdgcn_s_setprio(0);
            asm volatile("s_waitcnt vmcnt(4)" ::: "memory");
            __builtin_amdgcn_s_barrier();
            __builtin_amdgcn_sched_barrier(0);
        }
        // ---------------- window 1: acc[4..7] ----------------
        {
            l64x2 afr[4];
#pragma unroll
            for (int m = 0; m < 4; m++)
                afr[m] = *(const l64x2*)(A_rd + (wr * 128 + 64 + m * 16 + li) * 64 + colx);
            stage_chunk8(0, t + 2, Asrc, Bsrc, smem, w, laneoff);  // (t+2,B0)
            stage_chunk8(1, t + 2, Asrc, Bsrc, smem, w, laneoff);  // (t+2,B1)
            stage_chunk8(2, t + 2, Asrc, Bsrc, smem, w, laneoff);  // (t+2,A0)
            __builtin_amdgcn_s_setprio(1);
#pragma unroll
            for (int m = 0; m < 4; m++)
#pragma unroll
                for (int n = 0; n < 4; n++) {
                    acc[m + 4][n] = __builtin_amdgcn_mfma_f32_16x16x32_fp8_fp8(
                        afr[m].x, bfr[n].x, acc[m + 4][n], 0, 0, 0);
                    acc[m + 4][n] = __builtin_amdgcn_mfma_f32_16x16x32_fp8_fp8(
                        afr[m].y, bfr[n].y, acc[m + 4][n], 0, 0, 0);
                }
            __builtin_amdgcn_s_setprio(0);
            asm volatile("s_waitcnt vmcnt(4)" ::: "memory");
            __builtin_amdgcn_s_barrier();
            __builtin_amdgcn_sched_barrier(0);
        }
    }

    // ---- epilogue: per-row (sum_exp, sum_logit) over 256 columns ----
    __syncthreads();   // full drain (also retires dummy wrap prefetches)
    float* red = (float*)smem;   // [8][128][2] f32 = 8 KB, aliases Abuf0

#pragma unroll
    for (int m = 0; m < 8; m++) {
#pragma unroll
        for (int r = 0; r < 4; r++) {
            float s0 = softcap(acc[m][0][r]);
            float s1 = softcap(acc[m][1][r]);
            float s2 = softcap(acc[m][2][r]);
            float s3 = softcap(acc[m][3][r]);
            float se = __expf(s0) + __expf(s1) + __expf(s2) + __expf(s3);
            float st = s0 + s1 + s2 + s3;
#pragma unroll
            for (int off = 1; off < 16; off <<= 1) {
                se += __shfl_xor(se, off, 64);
                st += __shfl_xor(st, off, 64);
            }
            if (li == 0) {
                int rl = m * 16 + g * 4 + r;          // row within wave's 128
                int base = ((wr * 4 + wc) * 128 + rl) * 2;
                red[base + 0] = se;
                red[base + 1] = st;
            }
        }
    }
    __syncthreads();
    if (t0 < BM) {
        int r   = t0;
        int wr2 = r >> 7;
        int rr  = r & 127;
        float se = 0.f, st = 0.f;
#pragma unroll
        for (int q = 0; q < 4; q++) {
            int bq = ((wr2 * 4 + q) * 128 + rr) * 2;
            se += red[bq + 0];
            st += red[bq + 1];
        }
        part[(size_t)(brow * BM + r) * NCB + bcol] = make_float2(se, st);
    }
}

// ---------------------------------------------------------------------------
// K1 fallback (small ws): reg-staged f32->bf16, 128x128, BK=32.
// ---------------------------------------------------------------------------
__global__ __launch_bounds__(256) void gemm_partial_f32(
    const float* __restrict__ hidden, const float* __restrict__ weight,
    float2* __restrict__ part)
{
    __shared__ unsigned short sA[128 * 32];
    __shared__ unsigned short sB[128 * 32];
    __shared__ float red[4][64][2];

    const int bid  = blockIdx.x;
    const int brow = bid & 31;
    const int bcol = bid >> 5;
    const int t    = threadIdx.x;
    const int lane = t & 63;
    const int w    = t >> 6;
    const int wr   = w >> 1, wc = w & 1;

    const int srow = t >> 1;
    const int scol = (t & 1) * 16;
    const float* gA = hidden + (size_t)(brow * 128 + srow) * DIM + scol;
    const float* gB = weight + (size_t)(bcol * 128 + srow) * DIM + scol;
    unsigned short* wA = &sA[srow * 32 + scol];
    unsigned short* wB = &sB[srow * 32 + scol];

    f32x4 acc[4][4];
#pragma unroll
    for (int m = 0; m < 4; m++)
#pragma unroll
        for (int n = 0; n < 4; n++) acc[m][n] = (f32x4){0.f, 0.f, 0.f, 0.f};

    const unsigned short* pa = &sA[(wr * 64 + (lane & 15)) * 32 + (lane >> 4) * 8];
    const unsigned short* pb = &sB[(wc * 64 + (lane & 15)) * 32 + (lane >> 4) * 8];

    for (int k0 = 0; k0 < DIM; k0 += 32) {
        float4 a0 = *(const float4*)(gA + k0);
        float4 a1 = *(const float4*)(gA + k0 + 4);
        float4 a2 = *(const float4*)(gA + k0 + 8);
        float4 a3 = *(const float4*)(gA + k0 + 12);
        float4 b0 = *(const float4*)(gB + k0);
        float4 b1 = *(const float4*)(gB + k0 + 4);
        float4 b2 = *(const float4*)(gB + k0 + 8);
        float4 b3 = *(const float4*)(gB + k0 + 12);
        __syncthreads();
        u16x8 pa0 = { f2bf(a0.x), f2bf(a0.y), f2bf(a0.z), f2bf(a0.w),
                      f2bf(a1.x), f2bf(a1.y), f2bf(a1.z), f2bf(a1.w) };
        u16x8 pa1 = { f2bf(a2.x), f2bf(a2.y), f2bf(a2.z), f2bf(a2.w),
                      f2bf(a3.x), f2bf(a3.y), f2bf(a3.z), f2bf(a3.w) };
        u16x8 pb0 = { f2bf(b0.x), f2bf(b0.y), f2bf(b0.z), f2bf(b0.w),
                      f2bf(b1.x), f2bf(b1.y), f2bf(b1.z), f2bf(b1.w) };
        u16x8 pb1 = { f2bf(b2.x), f2bf(b2.y), f2bf(b2.z), f2bf(b2.w),
                      f2bf(b3.x), f2bf(b3.y), f2bf(b3.z), f2bf(b3.w) };
        *(u16x8*)wA = pa0;
        *(u16x8*)(wA + 8) = pa1;
        *(u16x8*)wB = pb0;
        *(u16x8*)(wB + 8) = pb1;
        __syncthreads();

        s16x8 afr[4], bfr[4];
#pragma unroll
        for (int m = 0; m < 4; m++) afr[m] = *(const s16x8*)(pa + m * 16 * 32);
#pragma unroll
        for (int n = 0; n < 4; n++) bfr[n] = *(const s16x8*)(pb + n * 16 * 32);
#pragma unroll
        for (int m = 0; m < 4; m++)
#pragma unroll
            for (int n = 0; n < 4; n++)
                acc[m][n] = __builtin_amdgcn_mfma_f32_16x16x32_bf16(
                    afr[m], bfr[n], acc[m][n], 0, 0, 0);
    }

    const int g  = lane >> 4;
    const int li = lane & 15;
#pragma unroll
    for (int m = 0; m < 4; m++) {
#pragma unroll
        for (int r = 0; r < 4; r++) {
            float s0 = softcap(acc[m][0][r]);
            float s1 = softcap(acc[m][1][r]);
            float s2 = softcap(acc[m][2][r]);
            float s3 = softcap(acc[m][3][r]);
            float se = __expf(s0) + __expf(s1) + __expf(s2) + __expf(s3);
            float st = s0 + s1 + s2 + s3;
#pragma unroll
            for (int off = 1; off < 16; off <<= 1) {
                se += __shfl_xor(se, off, 64);
                st += __shfl_xor(st, off, 64);
            }
            if (li == 0) {
                int rl = m * 16 + g * 4 + r;
                red[w][rl][0] = se;
                red[w][rl][1] = st;
            }
        }
    }
    __syncthreads();
    if (t < 128) {
        int r  = t;
        int wa = (r >> 6) * 2;
        int rr = r & 63;
        float se = red[wa][rr][0] + red[wa + 1][rr][0];
        float st = red[wa][rr][1] + red[wa + 1][rr][1];
        part[(size_t)(brow * 128 + r) * 256 + bcol] = make_float2(se, st);
    }
}

// ---------------------------------------------------------------------------
// K2: sum ncb column-block partials per row. 1 wave/row.
// ---------------------------------------------------------------------------
__global__ __launch_bounds__(256) void row_reduce(
    const float2* __restrict__ part, const int* __restrict__ targets,
    const float* __restrict__ xtbuf, float* __restrict__ rowbuf, int ncb)
{
    int row  = blockIdx.x * 4 + (threadIdx.x >> 6);
    int lane = threadIdx.x & 63;
    if (row >= N_ROWS) return;
    const float2* p = part + (size_t)row * ncb;
    float se = 0.f, st = 0.f;
    for (int q = lane; q < ncb; q += 64) {
        float2 u = p[q];
        se += u.x;
        st += u.y;
    }
#pragma unroll
    for (int off = 1; off < 64; off <<= 1) {
        se += __shfl_xor(se, off, 64);
        st += __shfl_xor(st, off, 64);
    }
    if (lane == 0) {
        float lse = logf(se);
        int   tgt = targets[row];
        float vf  = (tgt != IGNORE_IDX) ? 1.f : 0.f;
        float xt  = xtbuf[row];
        float nll = lse - xt;
        float smooth = lse - st * (1.f / (float)VOCAB);
        float rl = 0.9f * nll + 0.1f * smooth;
        rowbuf[row * 3 + 0] = rl * vf;
        rowbuf[row * 3 + 1] = lse * lse * vf;
        rowbuf[row * 3 + 2] = vf;
    }
}

// ---------------------------------------------------------------------------
// K3: deterministic final reduction -> scalar loss.
// ---------------------------------------------------------------------------
__global__ __launch_bounds__(256) void final_reduce(
    const float* __restrict__ rowbuf, float* __restrict__ out)
{
    __shared__ float sl[256], sz[256], sv[256];
    int t = threadIdx.x;
    float ls = 0.f, zs = 0.f, vs = 0.f;
    for (int r = t; r < N_ROWS; r += 256) {
        ls += rowbuf[r * 3 + 0];
        zs += rowbuf[r * 3 + 1];
        vs += rowbuf[r * 3 + 2];
    }
    sl[t] = ls; sz[t] = zs; sv[t] = vs;
    __syncthreads();
    for (int o = 128; o > 0; o >>= 1) {
        if (t < o) { sl[t] += sl[t + o]; sz[t] += sz[t + o]; sv[t] += sv[t + o]; }
        __syncthreads();
    }
    if (t == 0) {
        float nv = fmaxf(sv[0], 1.f);
        out[0] = sl[0] / nv + 1e-4f * (sz[0] / nv);
    }
}

// ---------------------------------------------------------------------------
extern "C" void kernel_launch(void* const* d_in, const int* in_sizes, int n_in,
                              void* d_out, int out_size, void* d_ws, size_t ws_size,
                              hipStream_t stream)
{
    const float* hidden  = (const float*)d_in[0];
    const float* weight  = (const float*)d_in[1];
    const int*   targets = (const int*)d_in[2];
    float*       out     = (float*)d_out;

    char* ws = (char*)d_ws;
    size_t off = 0;
    float2* part = (float2*)(ws + off);
    off += (size_t)N_ROWS * 256 * sizeof(float4);           // 16 MB slot (max layout)
    float* xtbuf = (float*)(ws + off);
    off += (size_t)N_ROWS * sizeof(float);
    float* rowbuf = (float*)(ws + off);
    off += (size_t)N_ROWS * 3 * sizeof(float);
    off = (off + 255) & ~(size_t)255;
    unsigned char* hid8 = (unsigned char*)(ws + off);
    off += (size_t)N_ROWS * DIM;                            // 8 MB
    unsigned char* wgt8 = (unsigned char*)(ws + off);
    off += (size_t)VOCAB * DIM;                             // 67 MB

    target_logit<<<N_ROWS / 4, 256, 0, stream>>>(hidden, weight, targets, xtbuf);

    if (ws_size >= off) {
        convert_fp8<<<2048, 256, 0, stream>>>(hidden, hid8, N_ROWS * (DIM / 16));
        convert_fp8<<<2048, 256, 0, stream>>>(weight, wgt8, VOCAB * (DIM / 16));
        gemm_fp8<<<ROW_TILES * (VOCAB / BN), 512, 0, stream>>>(hid8, wgt8, part);
        row_reduce<<<N_ROWS / 4, 256, 0, stream>>>(part, targets, xtbuf, rowbuf, NCB);
    } else {
        gemm_partial_f32<<<32 * 256, 256, 0, stream>>>(hidden, weight, part);
        row_reduce<<<N_ROWS / 4, 256, 0, stream>>>(part, targets, xtbuf, rowbuf, 256);
    }

    final_reduce<<<1, 256, 0, stream>>>(rowbuf, out);
}

// Round 7
// 481.958 us; speedup vs baseline: 4.3509x; 4.3509x over previous
//
#include <hip/hip_runtime.h>
#include <hip/hip_bf16.h>
#include <math.h>

// ChunkedLinearCrossEntropyLoss fused kernel for MI355X (gfx950) — R7
//
// hidden[4096,2048] f32, weight[32768,2048] f32, targets[4096] i32 -> scalar
//
//  Kc  convert_fp8  : f32 -> fp8 e4m3 copies, K-order pre-permuted so one
//                     ds_read_b128 yields both K-half MFMA fragments
//  K0  target_logit : x_t[row] = softcap(h[row].w[tgt[row]]) fp32 (exact)
//  K1  gemm_fp8     : 256x256 tile, BK=64, 8 waves, 2 windows/tile deep
//                     pipeline (vmcnt(4), swizzled LDS, setprio).
//                     R7 fixes vs R6: launch_bounds(512,2) (R6's (512,4)
//                     forced 128-VGPR cap -> acc spilled to scratch, 10 GB
//                     HBM traffic); swizzle uses (row>>1)&3 so each 16-lane
//                     quarter covers all 32 banks (R6's (row&3) hit 16).
//  K2  row_reduce   : sum column-block partials per row
//  K3  final_reduce : scalar loss
//
// fp8 buffer layout: row-major [row][2048 B]; within each 64-byte K-window t
// byte b holds original k = t*64 + ((b>>3)&1)*32 + ((b>>4)&3)*8 + (b&7).
// So 16B slot g of window t = fragment pair (kk=0, kk=1) for lane-group g.

#define N_ROWS 4096
#define DIM    2048
#define VOCAB  32768
#define IGNORE_IDX (-100)

#define BM 256
#define BN 256
#define BK 64
#define NT (DIM / BK)            // 32 K-tiles
#define NCB (VOCAB / BN)         // 128 column blocks
#define ROW_TILES (N_ROWS / BM)  // 16

typedef short s16x8 __attribute__((ext_vector_type(8)));
typedef unsigned short u16x8 __attribute__((ext_vector_type(8)));
typedef float f32x4 __attribute__((ext_vector_type(4)));
typedef long  l64x2 __attribute__((ext_vector_type(2)));

#define AS3(p) ((__attribute__((address_space(3))) void*)(p))
#define AS1(p) ((const __attribute__((address_space(1))) void*)(p))

// 20*tanh(x/20) via hardware exp; clamp keeps exp finite for any input.
__device__ __forceinline__ float softcap(float x) {
    x = fminf(80.f, fmaxf(-80.f, x));
    float e = __expf(x * 0.1f);
    return 20.f * (e - 1.f) * __builtin_amdgcn_rcpf(e + 1.f);
}

// f32 -> bf16 RNE (fallback path only)
__device__ __forceinline__ unsigned short f2bf(float f) {
    union { float f; unsigned u; } v; v.f = f;
    unsigned r = v.u + 0x7FFFu + ((v.u >> 16) & 1u);
    return (unsigned short)(r >> 16);
}

// ---------------------------------------------------------------------------
// Kc: f32 -> fp8 e4m3 with the fragment K-permutation baked in.
// ---------------------------------------------------------------------------
__global__ __launch_bounds__(256) void convert_fp8(
    const float* __restrict__ src, unsigned char* __restrict__ dst, int nchunk)
{
    int idx = blockIdx.x * 256 + threadIdx.x;
    int stride = gridDim.x * 256;
    for (int i = idx; i < nchunk; i += stride) {
        int row = i >> 7;
        int c   = i & 127;
        int t   = c >> 2;
        int g   = c & 3;
        const float* p = src + (size_t)row * DIM + t * 64 + g * 8;
        float4 a0 = *(const float4*)(p);
        float4 a1 = *(const float4*)(p + 4);
        float4 b0 = *(const float4*)(p + 32);
        float4 b1 = *(const float4*)(p + 36);
        int w0 = __builtin_amdgcn_cvt_pk_fp8_f32(a0.x, a0.y, 0, false);
        w0     = __builtin_amdgcn_cvt_pk_fp8_f32(a0.z, a0.w, w0, true);
        int w1 = __builtin_amdgcn_cvt_pk_fp8_f32(a1.x, a1.y, 0, false);
        w1     = __builtin_amdgcn_cvt_pk_fp8_f32(a1.z, a1.w, w1, true);
        int w2 = __builtin_amdgcn_cvt_pk_fp8_f32(b0.x, b0.y, 0, false);
        w2     = __builtin_amdgcn_cvt_pk_fp8_f32(b0.z, b0.w, w2, true);
        int w3 = __builtin_amdgcn_cvt_pk_fp8_f32(b1.x, b1.y, 0, false);
        w3     = __builtin_amdgcn_cvt_pk_fp8_f32(b1.z, b1.w, w3, true);
        *(int4*)(dst + (size_t)row * DIM + t * 64 + g * 16) =
            make_int4(w0, w1, w2, w3);
    }
}

// ---------------------------------------------------------------------------
// K0: x_t[row] = softcap(dot(hidden[row], weight[tgt])) fp32. 1 wave/row.
// ---------------------------------------------------------------------------
__global__ __launch_bounds__(256) void target_logit(
    const float* __restrict__ hidden, const float* __restrict__ weight,
    const int* __restrict__ targets, float* __restrict__ xtbuf)
{
    int row  = blockIdx.x * 4 + (threadIdx.x >> 6);
    int lane = threadIdx.x & 63;
    if (row >= N_ROWS) return;
    int tgt = targets[row];
    if (tgt < 0 || tgt >= VOCAB) {
        if (lane == 0) xtbuf[row] = 0.f;
        return;
    }
    const float4* h4 = (const float4*)(hidden + (size_t)row * DIM);
    const float4* w4 = (const float4*)(weight + (size_t)tgt * DIM);
    float d = 0.f;
#pragma unroll
    for (int j = 0; j < DIM / 4 / 64; j++) {
        float4 a = h4[lane + 64 * j];
        float4 b = w4[lane + 64 * j];
        d += a.x * b.x + a.y * b.y + a.z * b.z + a.w * b.w;
    }
#pragma unroll
    for (int off = 1; off < 64; off <<= 1) d += __shfl_xor(d, off, 64);
    if (lane == 0) xtbuf[row] = softcap(d);
}

// ---------------------------------------------------------------------------
// K1: 256x256 8-wave fp8 GEMM, 2 windows/tile, fused row partials.
//
// LDS (66.5 KB): Abuf[2] @ {0,16K}, Bbuf[2] @ {32K,48K}, dummy @64K.
// Rows are 64 B = 4 x 16B slots; phys slot = logical slot ^ ((row>>1)&3).
// Readers XOR; the stager inverse-permutes the global SOURCE and writes LDS
// linearly (both-sides-or-neither rule). Within a 16-lane quarter the reads
// then hit (row&1, slot) = all 8 combos x 2 lanes = 2 words/bank over all
// 32 banks — the b128 structural floor (0 counted conflicts).
//
// Chunks (8 KB = 1 global_load_lds per wave, 16 rows/instr):
//   B0=B rows[0,128); B1=B rows[128,256);
//   A0=A rows[0,64)u[128,192); A1=A rows[64,128)u[192,256).
// tile t W0 (acc[0..3]): read 4 B-pair + 4 A-pair b128; stage (t+1,A1)->
//   other buf; 32 MFMA; vmcnt(4); barrier.
// tile t W1 (acc[4..7]): read 4 A-pair; stage (t+2,{B0,B1,A0})->this buf
//   (those regions' reads retired in W0); 32 MFMA; vmcnt(4); barrier.
// FIFO: steady 4 outstanding after each wait; every confirmed chunk was
// issued >=2 windows earlier. ct>=NT chunks land in dummy (counts exact).
// ---------------------------------------------------------------------------
__device__ __forceinline__ void stage_chunk8(
    int kind, int ct, const unsigned char* Asrc, const unsigned char* Bsrc,
    unsigned char* smem, int w, int laneoff)
{
    // kind: 0=B0, 1=B1, 2=A0, 3=A1
    const int kcol = (ct & (NT - 1)) * 64;
    const int b = ct & 1;
    const int dum = (ct >= NT);
    const unsigned char* src;
    int base, row0;
    if (kind <= 1) {
        src = Bsrc; base = 32768 + b * 16384;
        row0 = kind * 128 + 16 * w;
    } else {
        src = Asrc; base = b * 16384;
        row0 = 16 * w + ((w >= 4) ? 64 : 0) + ((kind == 3) ? 64 : 0);
    }
    int l0 = dum ? 65536 : base + row0 * 64;
    __builtin_amdgcn_global_load_lds(
        AS1(src + (size_t)row0 * DIM + kcol + laneoff), AS3(smem + l0), 16, 0, 0);
}

__global__ __launch_bounds__(512, 2) void gemm_fp8(
    const unsigned char* __restrict__ A, const unsigned char* __restrict__ B,
    float2* __restrict__ part)
{
    __shared__ unsigned char smem[65536 + 1024] __attribute__((aligned(16)));

    const int bid  = blockIdx.x;
    const int brow = bid & (ROW_TILES - 1);   // 16 consecutive blocks share B panel
    const int bcol = bid >> 4;
    const int t0   = threadIdx.x;
    const int lane = t0 & 63;
    const int w    = t0 >> 6;                 // 0..7
    const int wr   = w >> 2;                  // 0..1 (M)
    const int wc   = w & 3;                   // 0..3 (N)
    const int li   = lane & 15;
    const int g    = lane >> 4;               // 0..3

    // fragment read: row = base16 + li; phys slot = g ^ ((li>>1)&3).
    const int colx = ((g ^ ((li >> 1) & 3)) << 4);

    // staging source (inverse swizzle): lane l covers row_local l>>2,
    // phys slot l&3 -> logical slot (l&3) ^ ((l>>3)&3).
    const int laneoff = (lane >> 2) * DIM + (((lane & 3) ^ ((lane >> 3) & 3)) << 4);

    const unsigned char* Asrc = A + (size_t)brow * BM * DIM;
    const unsigned char* Bsrc = B + (size_t)bcol * BN * DIM;

    f32x4 acc[8][4];
#pragma unroll
    for (int m = 0; m < 8; m++)
#pragma unroll
        for (int n = 0; n < 4; n++) acc[m][n] = (f32x4){0.f, 0.f, 0.f, 0.f};

    // ---- prologue: 7 chunks; vmcnt(4) confirms (0,B0),(0,B1),(0,A0) ----
    stage_chunk8(0, 0, Asrc, Bsrc, smem, w, laneoff);
    stage_chunk8(1, 0, Asrc, Bsrc, smem, w, laneoff);
    stage_chunk8(2, 0, Asrc, Bsrc, smem, w, laneoff);
    stage_chunk8(3, 0, Asrc, Bsrc, smem, w, laneoff);
    stage_chunk8(0, 1, Asrc, Bsrc, smem, w, laneoff);
    stage_chunk8(1, 1, Asrc, Bsrc, smem, w, laneoff);
    stage_chunk8(2, 1, Asrc, Bsrc, smem, w, laneoff);
    asm volatile("s_waitcnt vmcnt(4)" ::: "memory");
    __builtin_amdgcn_s_barrier();
    __builtin_amdgcn_sched_barrier(0);

    l64x2 bfr[4];

    for (int t = 0; t < NT; ++t) {
        const int b = t & 1;
        unsigned char* A_rd = smem + b * 16384;
        unsigned char* B_rd = smem + 32768 + b * 16384;

        // ---------------- window 0: acc[0..3] ----------------
        {
            l64x2 afr[4];
#pragma unroll
            for (int n = 0; n < 4; n++)
                bfr[n] = *(const l64x2*)(B_rd + (wc * 64 + n * 16 + li) * 64 + colx);
#pragma unroll
            for (int m = 0; m < 4; m++)
                afr[m] = *(const l64x2*)(A_rd + (wr * 128 + m * 16 + li) * 64 + colx);
            stage_chunk8(3, t + 1, Asrc, Bsrc, smem, w, laneoff);  // (t+1,A1)
            __builtin_amdgcn_s_setprio(1);
#pragma unroll
            for (int m = 0; m < 4; m++)
#pragma unroll
                for (int n = 0; n < 4; n++) {
                    acc[m][n] = __builtin_amdgcn_mfma_f32_16x16x32_fp8_fp8(
                        afr[m].x, bfr[n].x, acc[m][n], 0, 0, 0);
                    acc[m][n] = __builtin_amdgcn_mfma_f32_16x16x32_fp8_fp8(
                        afr[m].y, bfr[n].y, acc[m][n], 0, 0, 0);
                }
            __builtin_amdgcn_s_setprio(0);
            asm volatile("s_waitcnt vmcnt(4)" ::: "memory");
            __builtin_amdgcn_s_barrier();
            __builtin_amdgcn_sched_barrier(0);
        }
        // ---------------- window 1: acc[4..7] ----------------
        {
            l64x2 afr[4];
#pragma unroll
            for (int m = 0; m < 4; m++)
                afr[m] = *(const l64x2*)(A_rd + (wr * 128 + 64 + m * 16 + li) * 64 + colx);
            stage_chunk8(0, t + 2, Asrc, Bsrc, smem, w, laneoff);  // (t+2,B0)
            stage_chunk8(1, t + 2, Asrc, Bsrc, smem, w, laneoff);  // (t+2,B1)
            stage_chunk8(2, t + 2, Asrc, Bsrc, smem, w, laneoff);  // (t+2,A0)
            __builtin_amdgcn_s_setprio(1);
#pragma unroll
            for (int m = 0; m < 4; m++)
#pragma unroll
                for (int n = 0; n < 4; n++) {
                    acc[m + 4][n] = __builtin_amdgcn_mfma_f32_16x16x32_fp8_fp8(
                        afr[m].x, bfr[n].x, acc[m + 4][n], 0, 0, 0);
                    acc[m + 4][n] = __builtin_amdgcn_mfma_f32_16x16x32_fp8_fp8(
                        afr[m].y, bfr[n].y, acc[m + 4][n], 0, 0, 0);
                }
            __builtin_amdgcn_s_setprio(0);
            asm volatile("s_waitcnt vmcnt(4)" ::: "memory");
            __builtin_amdgcn_s_barrier();
            __builtin_amdgcn_sched_barrier(0);
        }
    }

    // ---- epilogue: per-row (sum_exp, sum_logit) over 256 columns ----
    __syncthreads();   // full drain (also retires dummy wrap prefetches)
    float* red = (float*)smem;   // [8][128][2] f32 = 8 KB, aliases Abuf0

#pragma unroll
    for (int m = 0; m < 8; m++) {
#pragma unroll
        for (int r = 0; r < 4; r++) {
            float s0 = softcap(acc[m][0][r]);
            float s1 = softcap(acc[m][1][r]);
            float s2 = softcap(acc[m][2][r]);
            float s3 = softcap(acc[m][3][r]);
            float se = __expf(s0) + __expf(s1) + __expf(s2) + __expf(s3);
            float st = s0 + s1 + s2 + s3;
#pragma unroll
            for (int off = 1; off < 16; off <<= 1) {
                se += __shfl_xor(se, off, 64);
                st += __shfl_xor(st, off, 64);
            }
            if (li == 0) {
                int rl = m * 16 + g * 4 + r;          // row within wave's 128
                int base = ((wr * 4 + wc) * 128 + rl) * 2;
                red[base + 0] = se;
                red[base + 1] = st;
            }
        }
    }
    __syncthreads();
    if (t0 < BM) {
        int r   = t0;
        int wr2 = r >> 7;
        int rr  = r & 127;
        float se = 0.f, st = 0.f;
#pragma unroll
        for (int q = 0; q < 4; q++) {
            int bq = ((wr2 * 4 + q) * 128 + rr) * 2;
            se += red[bq + 0];
            st += red[bq + 1];
        }
        part[(size_t)(brow * BM + r) * NCB + bcol] = make_float2(se, st);
    }
}

// ---------------------------------------------------------------------------
// K1 fallback (small ws): reg-staged f32->bf16, 128x128, BK=32.
// ---------------------------------------------------------------------------
__global__ __launch_bounds__(256) void gemm_partial_f32(
    const float* __restrict__ hidden, const float* __restrict__ weight,
    float2* __restrict__ part)
{
    __shared__ unsigned short sA[128 * 32];
    __shared__ unsigned short sB[128 * 32];
    __shared__ float red[4][64][2];

    const int bid  = blockIdx.x;
    const int brow = bid & 31;
    const int bcol = bid >> 5;
    const int t    = threadIdx.x;
    const int lane = t & 63;
    const int w    = t >> 6;
    const int wr   = w >> 1, wc = w & 1;

    const int srow = t >> 1;
    const int scol = (t & 1) * 16;
    const float* gA = hidden + (size_t)(brow * 128 + srow) * DIM + scol;
    const float* gB = weight + (size_t)(bcol * 128 + srow) * DIM + scol;
    unsigned short* wA = &sA[srow * 32 + scol];
    unsigned short* wB = &sB[srow * 32 + scol];

    f32x4 acc[4][4];
#pragma unroll
    for (int m = 0; m < 4; m++)
#pragma unroll
        for (int n = 0; n < 4; n++) acc[m][n] = (f32x4){0.f, 0.f, 0.f, 0.f};

    const unsigned short* pa = &sA[(wr * 64 + (lane & 15)) * 32 + (lane >> 4) * 8];
    const unsigned short* pb = &sB[(wc * 64 + (lane & 15)) * 32 + (lane >> 4) * 8];

    for (int k0 = 0; k0 < DIM; k0 += 32) {
        float4 a0 = *(const float4*)(gA + k0);
        float4 a1 = *(const float4*)(gA + k0 + 4);
        float4 a2 = *(const float4*)(gA + k0 + 8);
        float4 a3 = *(const float4*)(gA + k0 + 12);
        float4 b0 = *(const float4*)(gB + k0);
        float4 b1 = *(const float4*)(gB + k0 + 4);
        float4 b2 = *(const float4*)(gB + k0 + 8);
        float4 b3 = *(const float4*)(gB + k0 + 12);
        __syncthreads();
        u16x8 pa0 = { f2bf(a0.x), f2bf(a0.y), f2bf(a0.z), f2bf(a0.w),
                      f2bf(a1.x), f2bf(a1.y), f2bf(a1.z), f2bf(a1.w) };
        u16x8 pa1 = { f2bf(a2.x), f2bf(a2.y), f2bf(a2.z), f2bf(a2.w),
                      f2bf(a3.x), f2bf(a3.y), f2bf(a3.z), f2bf(a3.w) };
        u16x8 pb0 = { f2bf(b0.x), f2bf(b0.y), f2bf(b0.z), f2bf(b0.w),
                      f2bf(b1.x), f2bf(b1.y), f2bf(b1.z), f2bf(b1.w) };
        u16x8 pb1 = { f2bf(b2.x), f2bf(b2.y), f2bf(b2.z), f2bf(b2.w),
                      f2bf(b3.x), f2bf(b3.y), f2bf(b3.z), f2bf(b3.w) };
        *(u16x8*)wA = pa0;
        *(u16x8*)(wA + 8) = pa1;
        *(u16x8*)wB = pb0;
        *(u16x8*)(wB + 8) = pb1;
        __syncthreads();

        s16x8 afr[4], bfr[4];
#pragma unroll
        for (int m = 0; m < 4; m++) afr[m] = *(const s16x8*)(pa + m * 16 * 32);
#pragma unroll
        for (int n = 0; n < 4; n++) bfr[n] = *(const s16x8*)(pb + n * 16 * 32);
#pragma unroll
        for (int m = 0; m < 4; m++)
#pragma unroll
            for (int n = 0; n < 4; n++)
                acc[m][n] = __builtin_amdgcn_mfma_f32_16x16x32_bf16(
                    afr[m], bfr[n], acc[m][n], 0, 0, 0);
    }

    const int g  = lane >> 4;
    const int li = lane & 15;
#pragma unroll
    for (int m = 0; m < 4; m++) {
#pragma unroll
        for (int r = 0; r < 4; r++) {
            float s0 = softcap(acc[m][0][r]);
            float s1 = softcap(acc[m][1][r]);
            float s2 = softcap(acc[m][2][r]);
            float s3 = softcap(acc[m][3][r]);
            float se = __expf(s0) + __expf(s1) + __expf(s2) + __expf(s3);
            float st = s0 + s1 + s2 + s3;
#pragma unroll
            for (int off = 1; off < 16; off <<= 1) {
                se += __shfl_xor(se, off, 64);
                st += __shfl_xor(st, off, 64);
            }
            if (li == 0) {
                int rl = m * 16 + g * 4 + r;
                red[w][rl][0] = se;
                red[w][rl][1] = st;
            }
        }
    }
    __syncthreads();
    if (t < 128) {
        int r  = t;
        int wa = (r >> 6) * 2;
        int rr = r & 63;
        float se = red[wa][rr][0] + red[wa + 1][rr][0];
        float st = red[wa][rr][1] + red[wa + 1][rr][1];
        part[(size_t)(brow * 128 + r) * 256 + bcol] = make_float2(se, st);
    }
}

// ---------------------------------------------------------------------------
// K2: sum ncb column-block partials per row. 1 wave/row.
// ---------------------------------------------------------------------------
__global__ __launch_bounds__(256) void row_reduce(
    const float2* __restrict__ part, const int* __restrict__ targets,
    const float* __restrict__ xtbuf, float* __restrict__ rowbuf, int ncb)
{
    int row  = blockIdx.x * 4 + (threadIdx.x >> 6);
    int lane = threadIdx.x & 63;
    if (row >= N_ROWS) return;
    const float2* p = part + (size_t)row * ncb;
    float se = 0.f, st = 0.f;
    for (int q = lane; q < ncb; q += 64) {
        float2 u = p[q];
        se += u.x;
        st += u.y;
    }
#pragma unroll
    for (int off = 1; off < 64; off <<= 1) {
        se += __shfl_xor(se, off, 64);
        st += __shfl_xor(st, off, 64);
    }
    if (lane == 0) {
        float lse = logf(se);
        int   tgt = targets[row];
        float vf  = (tgt != IGNORE_IDX) ? 1.f : 0.f;
        float xt  = xtbuf[row];
        float nll = lse - xt;
        float smooth = lse - st * (1.f / (float)VOCAB);
        float rl = 0.9f * nll + 0.1f * smooth;
        rowbuf[row * 3 + 0] = rl * vf;
        rowbuf[row * 3 + 1] = lse * lse * vf;
        rowbuf[row * 3 + 2] = vf;
    }
}

// ---------------------------------------------------------------------------
// K3: deterministic final reduction -> scalar loss.
// ---------------------------------------------------------------------------
__global__ __launch_bounds__(256) void final_reduce(
    const float* __restrict__ rowbuf, float* __restrict__ out)
{
    __shared__ float sl[256], sz[256], sv[256];
    int t = threadIdx.x;
    float ls = 0.f, zs = 0.f, vs = 0.f;
    for (int r = t; r < N_ROWS; r += 256) {
        ls += rowbuf[r * 3 + 0];
        zs += rowbuf[r * 3 + 1];
        vs += rowbuf[r * 3 + 2];
    }
    sl[t] = ls; sz[t] = zs; sv[t] = vs;
    __syncthreads();
    for (int o = 128; o > 0; o >>= 1) {
        if (t < o) { sl[t] += sl[t + o]; sz[t] += sz[t + o]; sv[t] += sv[t + o]; }
        __syncthreads();
    }
    if (t == 0) {
        float nv = fmaxf(sv[0], 1.f);
        out[0] = sl[0] / nv + 1e-4f * (sz[0] / nv);
    }
}

// ---------------------------------------------------------------------------
extern "C" void kernel_launch(void* const* d_in, const int* in_sizes, int n_in,
                              void* d_out, int out_size, void* d_ws, size_t ws_size,
                              hipStream_t stream)
{
    const float* hidden  = (const float*)d_in[0];
    const float* weight  = (const float*)d_in[1];
    const int*   targets = (const int*)d_in[2];
    float*       out     = (float*)d_out;

    char* ws = (char*)d_ws;
    size_t off = 0;
    float2* part = (float2*)(ws + off);
    off += (size_t)N_ROWS * 256 * sizeof(float4);           // 16 MB slot (max layout)
    float* xtbuf = (float*)(ws + off);
    off += (size_t)N_ROWS * sizeof(float);
    float* rowbuf = (float*)(ws + off);
    off += (size_t)N_ROWS * 3 * sizeof(float);
    off = (off + 255) & ~(size_t)255;
    unsigned char* hid8 = (unsigned char*)(ws + off);
    off += (size_t)N_ROWS * DIM;                            // 8 MB
    unsigned char* wgt8 = (unsigned char*)(ws + off);
    off += (size_t)VOCAB * DIM;                             // 67 MB

    target_logit<<<N_ROWS / 4, 256, 0, stream>>>(hidden, weight, targets, xtbuf);

    if (ws_size >= off) {
        convert_fp8<<<2048, 256, 0, stream>>>(hidden, hid8, N_ROWS * (DIM / 16));
        convert_fp8<<<2048, 256, 0, stream>>>(weight, wgt8, VOCAB * (DIM / 16));
        gemm_fp8<<<ROW_TILES * (VOCAB / BN), 512, 0, stream>>>(hid8, wgt8, part);
        row_reduce<<<N_ROWS / 4, 256, 0, stream>>>(part, targets, xtbuf, rowbuf, NCB);
    } else {
        gemm_partial_f32<<<32 * 256, 256, 0, stream>>>(hidden, weight, part);
        row_reduce<<<N_ROWS / 4, 256, 0, stream>>>(part, targets, xtbuf, rowbuf, 256);
    }

    final_reduce<<<1, 256, 0, stream>>>(rowbuf, out);
}

// Round 8
// 452.622 us; speedup vs baseline: 4.6329x; 1.0648x over previous
//
#include <hip/hip_runtime.h>
#include <hip/hip_bf16.h>
#include <math.h>

// ChunkedLinearCrossEntropyLoss fused kernel for MI355X (gfx950) — R8
//
// hidden[4096,2048] f32, weight[32768,2048] f32, targets[4096] i32 -> scalar
//
//  Kc  convert_fp8  : f32 -> fp8 e4m3 copies (natural k order)
//  K0  target_logit : x_t[row] = softcap(h[row].w[tgt[row]]) fp32 (exact)
//  K1  gemm_mx      : 256x256 tile, BK=128, 8 waves, MX-scaled fp8 MFMA
//                     (mfma_scale_f32_16x16x128_f8f6f4, unit scales 0x7F ->
//                     numerically identical to R7's e4m3 path, 2x the rate).
//                     2 windows/tile deep pipeline (vmcnt(8)), 8-slot XOR
//                     swizzle on 128B rows, setprio.
//  K2  row_reduce   : sum column-block partials per row
//  K3  final_reduce : scalar loss

#define N_ROWS 4096
#define DIM    2048
#define VOCAB  32768
#define IGNORE_IDX (-100)

#define BM 256
#define BN 256
#define BK 128
#define NT (DIM / BK)            // 16 K-tiles
#define NCB (VOCAB / BN)         // 128 column blocks
#define ROW_TILES (N_ROWS / BM)  // 16

typedef short s16x8 __attribute__((ext_vector_type(8)));
typedef unsigned short u16x8 __attribute__((ext_vector_type(8)));
typedef float f32x4 __attribute__((ext_vector_type(4)));
typedef int   i32x4 __attribute__((ext_vector_type(4)));
typedef int   i32x8 __attribute__((ext_vector_type(8)));

#define AS3(p) ((__attribute__((address_space(3))) void*)(p))
#define AS1(p) ((const __attribute__((address_space(1))) void*)(p))

#define UNIT_SCALE 0x7F7F7F7F    // E8M0 127 = 2^0 in every byte

// 20*tanh(x/20) via hardware exp; clamp keeps exp finite for any input.
__device__ __forceinline__ float softcap(float x) {
    x = fminf(80.f, fmaxf(-80.f, x));
    float e = __expf(x * 0.1f);
    return 20.f * (e - 1.f) * __builtin_amdgcn_rcpf(e + 1.f);
}

// f32 -> bf16 RNE (fallback path only)
__device__ __forceinline__ unsigned short f2bf(float f) {
    union { float f; unsigned u; } v; v.f = f;
    unsigned r = v.u + 0x7FFFu + ((v.u >> 16) & 1u);
    return (unsigned short)(r >> 16);
}

// ---------------------------------------------------------------------------
// Kc: f32 -> fp8 e4m3, natural (linear) k order. One thread = 16 elems.
// ---------------------------------------------------------------------------
__global__ __launch_bounds__(256) void convert_fp8(
    const float* __restrict__ src, unsigned char* __restrict__ dst, int nchunk)
{
    int idx = blockIdx.x * 256 + threadIdx.x;
    int stride = gridDim.x * 256;
    for (int i = idx; i < nchunk; i += stride) {
        const float* p = src + (size_t)i * 16;
        float4 a0 = *(const float4*)(p);
        float4 a1 = *(const float4*)(p + 4);
        float4 b0 = *(const float4*)(p + 8);
        float4 b1 = *(const float4*)(p + 12);
        int w0 = __builtin_amdgcn_cvt_pk_fp8_f32(a0.x, a0.y, 0, false);
        w0     = __builtin_amdgcn_cvt_pk_fp8_f32(a0.z, a0.w, w0, true);
        int w1 = __builtin_amdgcn_cvt_pk_fp8_f32(a1.x, a1.y, 0, false);
        w1     = __builtin_amdgcn_cvt_pk_fp8_f32(a1.z, a1.w, w1, true);
        int w2 = __builtin_amdgcn_cvt_pk_fp8_f32(b0.x, b0.y, 0, false);
        w2     = __builtin_amdgcn_cvt_pk_fp8_f32(b0.z, b0.w, w2, true);
        int w3 = __builtin_amdgcn_cvt_pk_fp8_f32(b1.x, b1.y, 0, false);
        w3     = __builtin_amdgcn_cvt_pk_fp8_f32(b1.z, b1.w, w3, true);
        *(int4*)(dst + (size_t)i * 16) = make_int4(w0, w1, w2, w3);
    }
}

// ---------------------------------------------------------------------------
// K0: x_t[row] = softcap(dot(hidden[row], weight[tgt])) fp32. 1 wave/row.
// ---------------------------------------------------------------------------
__global__ __launch_bounds__(256) void target_logit(
    const float* __restrict__ hidden, const float* __restrict__ weight,
    const int* __restrict__ targets, float* __restrict__ xtbuf)
{
    int row  = blockIdx.x * 4 + (threadIdx.x >> 6);
    int lane = threadIdx.x & 63;
    if (row >= N_ROWS) return;
    int tgt = targets[row];
    if (tgt < 0 || tgt >= VOCAB) {
        if (lane == 0) xtbuf[row] = 0.f;
        return;
    }
    const float4* h4 = (const float4*)(hidden + (size_t)row * DIM);
    const float4* w4 = (const float4*)(weight + (size_t)tgt * DIM);
    float d = 0.f;
#pragma unroll
    for (int j = 0; j < DIM / 4 / 64; j++) {
        float4 a = h4[lane + 64 * j];
        float4 b = w4[lane + 64 * j];
        d += a.x * b.x + a.y * b.y + a.z * b.z + a.w * b.w;
    }
#pragma unroll
    for (int off = 1; off < 64; off <<= 1) d += __shfl_xor(d, off, 64);
    if (lane == 0) xtbuf[row] = softcap(d);
}

// ---------------------------------------------------------------------------
// K1: 256x256 8-wave MX-fp8 GEMM (K=128/MFMA), 2 windows/tile, fused partials.
//
// LDS (129+ KB): Abuf[2] @ {0,32K}, Bbuf[2] @ {64K,96K}, dummy @128K (1KB).
// Tile t reads buf t&1. Rows are 128 B = 8 x 16B slots;
//   phys slot = logical slot ^ (row&7)
// Readers XOR; stager inverse-permutes the global SOURCE, LDS dest linear.
// Fragment read (lane l: row base+li, li=l&15, g=l>>4): logical slots 2g and
// 2g+1 -> per b128, 64 lanes spread 8/slot = uniform 8 words/bank (b128 floor).
//
// Chunks = 64 rows, 1 global_load_lds per wave (8 rows each):
//   A chunks ci=0..3 = rows [64ci,64ci+64); same for B.
//   W0 reads A ci{0,2} (rows wr*128+[0,64)) + all B; W1 reads A ci{1,3}.
// Schedule (per wave instr counts):  W0: issue 2 = (t+1, A ci1,ci3) -> buf
//   (t+1)&1; wait vmcnt(8) confirms (t, A ci1,ci3).  W1: issue 6 = (t+2,
//   B ci0-3 + A ci0,ci2) -> buf t&1 (regions' reads retired in W0); wait
//   vmcnt(8) confirms (t+1, B+Aci0,2).  ct>=NT -> dummy (counts stay exact).
// ---------------------------------------------------------------------------
__device__ __forceinline__ void stage_mx(
    int isB, int ci, int ct, const unsigned char* Asrc, const unsigned char* Bsrc,
    unsigned char* smem, int w, int laneoff)
{
    const int kcol = (ct & (NT - 1)) * BK;
    const int row0 = ci * 64 + 8 * w;
    const int base = (isB ? 65536 : 0) + (ct & 1) * 32768;
    const int dest = (ct >= NT) ? 131072 : base + row0 * 128;
    const unsigned char* src = (isB ? Bsrc : Asrc) + (size_t)row0 * DIM + kcol + laneoff;
    __builtin_amdgcn_global_load_lds(AS1(src), AS3(smem + dest), 16, 0, 0);
}

__global__ __launch_bounds__(512, 2) void gemm_mx(
    const unsigned char* __restrict__ A, const unsigned char* __restrict__ B,
    float2* __restrict__ part)
{
    __shared__ unsigned char smem[131072 + 1024] __attribute__((aligned(16)));

    const int bid  = blockIdx.x;
    const int brow = bid & (ROW_TILES - 1);   // 16 consecutive blocks share B panel
    const int bcol = bid >> 4;
    const int t0   = threadIdx.x;
    const int lane = t0 & 63;
    const int w    = t0 >> 6;                 // 0..7
    const int wr   = w >> 2;                  // 0..1 (M)
    const int wc   = w & 3;                   // 0..3 (N)
    const int li   = lane & 15;
    const int g    = lane >> 4;               // 0..3 (k-group: k = g*32+[0,32))

    // swizzled byte offsets of the two 16B halves of this lane's fragment
    const int colx0 = (((2 * g)     ^ (li & 7)) << 4);
    const int colx1 = (((2 * g + 1) ^ (li & 7)) << 4);

    // staging source (inverse swizzle): lane l covers row_local l>>3,
    // phys slot l&7 -> logical slot (l&7)^(l>>3).
    const int laneoff = (lane >> 3) * DIM + (((lane & 7) ^ (lane >> 3)) << 4);

    const unsigned char* Asrc = A + (size_t)brow * BM * DIM;
    const unsigned char* Bsrc = B + (size_t)bcol * BN * DIM;

    f32x4 acc[8][4];
#pragma unroll
    for (int m = 0; m < 8; m++)
#pragma unroll
        for (int n = 0; n < 4; n++) acc[m][n] = (f32x4){0.f, 0.f, 0.f, 0.f};

    // ---- prologue: 14 instrs; vmcnt(8) confirms (0, B ci0-3 + A ci0,ci2) ----
    stage_mx(1, 0, 0, Asrc, Bsrc, smem, w, laneoff);
    stage_mx(1, 1, 0, Asrc, Bsrc, smem, w, laneoff);
    stage_mx(1, 2, 0, Asrc, Bsrc, smem, w, laneoff);
    stage_mx(1, 3, 0, Asrc, Bsrc, smem, w, laneoff);
    stage_mx(0, 0, 0, Asrc, Bsrc, smem, w, laneoff);
    stage_mx(0, 2, 0, Asrc, Bsrc, smem, w, laneoff);
    stage_mx(0, 1, 0, Asrc, Bsrc, smem, w, laneoff);
    stage_mx(0, 3, 0, Asrc, Bsrc, smem, w, laneoff);
    stage_mx(1, 0, 1, Asrc, Bsrc, smem, w, laneoff);
    stage_mx(1, 1, 1, Asrc, Bsrc, smem, w, laneoff);
    stage_mx(1, 2, 1, Asrc, Bsrc, smem, w, laneoff);
    stage_mx(1, 3, 1, Asrc, Bsrc, smem, w, laneoff);
    stage_mx(0, 0, 1, Asrc, Bsrc, smem, w, laneoff);
    stage_mx(0, 2, 1, Asrc, Bsrc, smem, w, laneoff);
    asm volatile("s_waitcnt vmcnt(8)" ::: "memory");
    __builtin_amdgcn_s_barrier();
    __builtin_amdgcn_sched_barrier(0);

    i32x8 bfr[4];

    for (int t = 0; t < NT; ++t) {
        const int b = t & 1;
        unsigned char* A_rd = smem + b * 32768;
        unsigned char* B_rd = smem + 65536 + b * 32768;

        // ---------------- window 0: acc[0..3] ----------------
        {
            i32x8 afr[4];
#pragma unroll
            for (int n = 0; n < 4; n++) {
                int ro = (wc * 64 + n * 16 + li) * 128;
                i32x4 lo = *(const i32x4*)(B_rd + ro + colx0);
                i32x4 hi = *(const i32x4*)(B_rd + ro + colx1);
                bfr[n] = (i32x8){lo[0], lo[1], lo[2], lo[3],
                                 hi[0], hi[1], hi[2], hi[3]};
            }
#pragma unroll
            for (int m = 0; m < 4; m++) {
                int ro = (wr * 128 + m * 16 + li) * 128;
                i32x4 lo = *(const i32x4*)(A_rd + ro + colx0);
                i32x4 hi = *(const i32x4*)(A_rd + ro + colx1);
                afr[m] = (i32x8){lo[0], lo[1], lo[2], lo[3],
                                 hi[0], hi[1], hi[2], hi[3]};
            }
            stage_mx(0, 1, t + 1, Asrc, Bsrc, smem, w, laneoff);
            stage_mx(0, 3, t + 1, Asrc, Bsrc, smem, w, laneoff);
            __builtin_amdgcn_s_setprio(1);
#pragma unroll
            for (int m = 0; m < 4; m++)
#pragma unroll
                for (int n = 0; n < 4; n++)
                    acc[m][n] = __builtin_amdgcn_mfma_scale_f32_16x16x128_f8f6f4(
                        afr[m], bfr[n], acc[m][n],
                        0, 0, 0, UNIT_SCALE, 0, UNIT_SCALE);
            __builtin_amdgcn_s_setprio(0);
            asm volatile("s_waitcnt vmcnt(8)" ::: "memory");
            __builtin_amdgcn_s_barrier();
            __builtin_amdgcn_sched_barrier(0);
        }
        // ---------------- window 1: acc[4..7] ----------------
        {
            i32x8 afr[4];
#pragma unroll
            for (int m = 0; m < 4; m++) {
                int ro = (wr * 128 + 64 + m * 16 + li) * 128;
                i32x4 lo = *(const i32x4*)(A_rd + ro + colx0);
                i32x4 hi = *(const i32x4*)(A_rd + ro + colx1);
                afr[m] = (i32x8){lo[0], lo[1], lo[2], lo[3],
                                 hi[0], hi[1], hi[2], hi[3]};
            }
            stage_mx(1, 0, t + 2, Asrc, Bsrc, smem, w, laneoff);
            stage_mx(1, 1, t + 2, Asrc, Bsrc, smem, w, laneoff);
            stage_mx(1, 2, t + 2, Asrc, Bsrc, smem, w, laneoff);
            stage_mx(1, 3, t + 2, Asrc, Bsrc, smem, w, laneoff);
            stage_mx(0, 0, t + 2, Asrc, Bsrc, smem, w, laneoff);
            stage_mx(0, 2, t + 2, Asrc, Bsrc, smem, w, laneoff);
            __builtin_amdgcn_s_setprio(1);
#pragma unroll
            for (int m = 0; m < 4; m++)
#pragma unroll
                for (int n = 0; n < 4; n++)
                    acc[m + 4][n] = __builtin_amdgcn_mfma_scale_f32_16x16x128_f8f6f4(
                        afr[m], bfr[n], acc[m + 4][n],
                        0, 0, 0, UNIT_SCALE, 0, UNIT_SCALE);
            __builtin_amdgcn_s_setprio(0);
            asm volatile("s_waitcnt vmcnt(8)" ::: "memory");
            __builtin_amdgcn_s_barrier();
            __builtin_amdgcn_sched_barrier(0);
        }
    }

    // ---- epilogue: per-row (sum_exp, sum_logit) over 256 columns ----
    __syncthreads();   // full drain (also retires dummy wrap prefetches)
    float* red = (float*)smem;   // [8][128][2] f32 = 8 KB, aliases Abuf0
                                 // (last tile 15 reads buf1 @32K/@96K — safe)
#pragma unroll
    for (int m = 0; m < 8; m++) {
#pragma unroll
        for (int r = 0; r < 4; r++) {
            float s0 = softcap(acc[m][0][r]);
            float s1 = softcap(acc[m][1][r]);
            float s2 = softcap(acc[m][2][r]);
            float s3 = softcap(acc[m][3][r]);
            float se = __expf(s0) + __expf(s1) + __expf(s2) + __expf(s3);
            float st = s0 + s1 + s2 + s3;
#pragma unroll
            for (int off = 1; off < 16; off <<= 1) {
                se += __shfl_xor(se, off, 64);
                st += __shfl_xor(st, off, 64);
            }
            if (li == 0) {
                int rl = m * 16 + g * 4 + r;          // row within wave's 128
                int base = ((wr * 4 + wc) * 128 + rl) * 2;
                red[base + 0] = se;
                red[base + 1] = st;
            }
        }
    }
    __syncthreads();
    if (t0 < BM) {
        int r   = t0;
        int wr2 = r >> 7;
        int rr  = r & 127;
        float se = 0.f, st = 0.f;
#pragma unroll
        for (int q = 0; q < 4; q++) {
            int bq = ((wr2 * 4 + q) * 128 + rr) * 2;
            se += red[bq + 0];
            st += red[bq + 1];
        }
        part[(size_t)(brow * BM + r) * NCB + bcol] = make_float2(se, st);
    }
}

// ---------------------------------------------------------------------------
// K1 fallback (small ws): reg-staged f32->bf16, 128x128, BK=32.
// ---------------------------------------------------------------------------
__global__ __launch_bounds__(256) void gemm_partial_f32(
    const float* __restrict__ hidden, const float* __restrict__ weight,
    float2* __restrict__ part)
{
    __shared__ unsigned short sA[128 * 32];
    __shared__ unsigned short sB[128 * 32];
    __shared__ float red[4][64][2];

    const int bid  = blockIdx.x;
    const int brow = bid & 31;
    const int bcol = bid >> 5;
    const int t    = threadIdx.x;
    const int lane = t & 63;
    const int w    = t >> 6;
    const int wr   = w >> 1, wc = w & 1;

    const int srow = t >> 1;
    const int scol = (t & 1) * 16;
    const float* gA = hidden + (size_t)(brow * 128 + srow) * DIM + scol;
    const float* gB = weight + (size_t)(bcol * 128 + srow) * DIM + scol;
    unsigned short* wA = &sA[srow * 32 + scol];
    unsigned short* wB = &sB[srow * 32 + scol];

    f32x4 acc[4][4];
#pragma unroll
    for (int m = 0; m < 4; m++)
#pragma unroll
        for (int n = 0; n < 4; n++) acc[m][n] = (f32x4){0.f, 0.f, 0.f, 0.f};

    const unsigned short* pa = &sA[(wr * 64 + (lane & 15)) * 32 + (lane >> 4) * 8];
    const unsigned short* pb = &sB[(wc * 64 + (lane & 15)) * 32 + (lane >> 4) * 8];

    for (int k0 = 0; k0 < DIM; k0 += 32) {
        float4 a0 = *(const float4*)(gA + k0);
        float4 a1 = *(const float4*)(gA + k0 + 4);
        float4 a2 = *(const float4*)(gA + k0 + 8);
        float4 a3 = *(const float4*)(gA + k0 + 12);
        float4 b0 = *(const float4*)(gB + k0);
        float4 b1 = *(const float4*)(gB + k0 + 4);
        float4 b2 = *(const float4*)(gB + k0 + 8);
        float4 b3 = *(const float4*)(gB + k0 + 12);
        __syncthreads();
        u16x8 pa0 = { f2bf(a0.x), f2bf(a0.y), f2bf(a0.z), f2bf(a0.w),
                      f2bf(a1.x), f2bf(a1.y), f2bf(a1.z), f2bf(a1.w) };
        u16x8 pa1 = { f2bf(a2.x), f2bf(a2.y), f2bf(a2.z), f2bf(a2.w),
                      f2bf(a3.x), f2bf(a3.y), f2bf(a3.z), f2bf(a3.w) };
        u16x8 pb0 = { f2bf(b0.x), f2bf(b0.y), f2bf(b0.z), f2bf(b0.w),
                      f2bf(b1.x), f2bf(b1.y), f2bf(b1.z), f2bf(b1.w) };
        u16x8 pb1 = { f2bf(b2.x), f2bf(b2.y), f2bf(b2.z), f2bf(b2.w),
                      f2bf(b3.x), f2bf(b3.y), f2bf(b3.z), f2bf(b3.w) };
        *(u16x8*)wA = pa0;
        *(u16x8*)(wA + 8) = pa1;
        *(u16x8*)wB = pb0;
        *(u16x8*)(wB + 8) = pb1;
        __syncthreads();

        s16x8 afr[4], bfr[4];
#pragma unroll
        for (int m = 0; m < 4; m++) afr[m] = *(const s16x8*)(pa + m * 16 * 32);
#pragma unroll
        for (int n = 0; n < 4; n++) bfr[n] = *(const s16x8*)(pb + n * 16 * 32);
#pragma unroll
        for (int m = 0; m < 4; m++)
#pragma unroll
            for (int n = 0; n < 4; n++)
                acc[m][n] = __builtin_amdgcn_mfma_f32_16x16x32_bf16(
                    afr[m], bfr[n], acc[m][n], 0, 0, 0);
    }

    const int g  = lane >> 4;
    const int li = lane & 15;
#pragma unroll
    for (int m = 0; m < 4; m++) {
#pragma unroll
        for (int r = 0; r < 4; r++) {
            float s0 = softcap(acc[m][0][r]);
            float s1 = softcap(acc[m][1][r]);
            float s2 = softcap(acc[m][2][r]);
            float s3 = softcap(acc[m][3][r]);
            float se = __expf(s0) + __expf(s1) + __expf(s2) + __expf(s3);
            float st = s0 + s1 + s2 + s3;
#pragma unroll
            for (int off = 1; off < 16; off <<= 1) {
                se += __shfl_xor(se, off, 64);
                st += __shfl_xor(st, off, 64);
            }
            if (li == 0) {
                int rl = m * 16 + g * 4 + r;
                red[w][rl][0] = se;
                red[w][rl][1] = st;
            }
        }
    }
    __syncthreads();
    if (t < 128) {
        int r  = t;
        int wa = (r >> 6) * 2;
        int rr = r & 63;
        float se = red[wa][rr][0] + red[wa + 1][rr][0];
        float st = red[wa][rr][1] + red[wa + 1][rr][1];
        part[(size_t)(brow * 128 + r) * 256 + bcol] = make_float2(se, st);
    }
}

// ---------------------------------------------------------------------------
// K2: sum ncb column-block partials per row. 1 wave/row.
// ---------------------------------------------------------------------------
__global__ __launch_bounds__(256) void row_reduce(
    const float2* __restrict__ part, const int* __restrict__ targets,
    const float* __restrict__ xtbuf, float* __restrict__ rowbuf, int ncb)
{
    int row  = blockIdx.x * 4 + (threadIdx.x >> 6);
    int lane = threadIdx.x & 63;
    if (row >= N_ROWS) return;
    const float2* p = part + (size_t)row * ncb;
    float se = 0.f, st = 0.f;
    for (int q = lane; q < ncb; q += 64) {
        float2 u = p[q];
        se += u.x;
        st += u.y;
    }
#pragma unroll
    for (int off = 1; off < 64; off <<= 1) {
        se += __shfl_xor(se, off, 64);
        st += __shfl_xor(st, off, 64);
    }
    if (lane == 0) {
        float lse = logf(se);
        int   tgt = targets[row];
        float vf  = (tgt != IGNORE_IDX) ? 1.f : 0.f;
        float xt  = xtbuf[row];
        float nll = lse - xt;
        float smooth = lse - st * (1.f / (float)VOCAB);
        float rl = 0.9f * nll + 0.1f * smooth;
        rowbuf[row * 3 + 0] = rl * vf;
        rowbuf[row * 3 + 1] = lse * lse * vf;
        rowbuf[row * 3 + 2] = vf;
    }
}

// ---------------------------------------------------------------------------
// K3: deterministic final reduction -> scalar loss.
// ---------------------------------------------------------------------------
__global__ __launch_bounds__(256) void final_reduce(
    const float* __restrict__ rowbuf, float* __restrict__ out)
{
    __shared__ float sl[256], sz[256], sv[256];
    int t = threadIdx.x;
    float ls = 0.f, zs = 0.f, vs = 0.f;
    for (int r = t; r < N_ROWS; r += 256) {
        ls += rowbuf[r * 3 + 0];
        zs += rowbuf[r * 3 + 1];
        vs += rowbuf[r * 3 + 2];
    }
    sl[t] = ls; sz[t] = zs; sv[t] = vs;
    __syncthreads();
    for (int o = 128; o > 0; o >>= 1) {
        if (t < o) { sl[t] += sl[t + o]; sz[t] += sz[t + o]; sv[t] += sv[t + o]; }
        __syncthreads();
    }
    if (t == 0) {
        float nv = fmaxf(sv[0], 1.f);
        out[0] = sl[0] / nv + 1e-4f * (sz[0] / nv);
    }
}

// ---------------------------------------------------------------------------
extern "C" void kernel_launch(void* const* d_in, const int* in_sizes, int n_in,
                              void* d_out, int out_size, void* d_ws, size_t ws_size,
                              hipStream_t stream)
{
    const float* hidden  = (const float*)d_in[0];
    const float* weight  = (const float*)d_in[1];
    const int*   targets = (const int*)d_in[2];
    float*       out     = (float*)d_out;

    char* ws = (char*)d_ws;
    size_t off = 0;
    float2* part = (float2*)(ws + off);
    off += (size_t)N_ROWS * 256 * sizeof(float4);           // 16 MB slot (max layout)
    float* xtbuf = (float*)(ws + off);
    off += (size_t)N_ROWS * sizeof(float);
    float* rowbuf = (float*)(ws + off);
    off += (size_t)N_ROWS * 3 * sizeof(float);
    off = (off + 255) & ~(size_t)255;
    unsigned char* hid8 = (unsigned char*)(ws + off);
    off += (size_t)N_ROWS * DIM;                            // 8 MB
    unsigned char* wgt8 = (unsigned char*)(ws + off);
    off += (size_t)VOCAB * DIM;                             // 67 MB

    target_logit<<<N_ROWS / 4, 256, 0, stream>>>(hidden, weight, targets, xtbuf);

    if (ws_size >= off) {
        convert_fp8<<<2048, 256, 0, stream>>>(hidden, hid8, N_ROWS * (DIM / 16));
        convert_fp8<<<2048, 256, 0, stream>>>(weight, wgt8, VOCAB * (DIM / 16));
        gemm_mx<<<ROW_TILES * (VOCAB / BN), 512, 0, stream>>>(hid8, wgt8, part);
        row_reduce<<<N_ROWS / 4, 256, 0, stream>>>(part, targets, xtbuf, rowbuf, NCB);
    } else {
        gemm_partial_f32<<<32 * 256, 256, 0, stream>>>(hidden, weight, part);
        row_reduce<<<N_ROWS / 4, 256, 0, stream>>>(part, targets, xtbuf, rowbuf, 256);
    }

    final_reduce<<<1, 256, 0, stream>>>(rowbuf, out);
}

// Round 9
// 447.706 us; speedup vs baseline: 4.6838x; 1.0110x over previous
//
#include <hip/hip_runtime.h>
#include <hip/hip_bf16.h>
#include <math.h>

// ChunkedLinearCrossEntropyLoss fused kernel for MI355X (gfx950) — R9
//
// hidden[4096,2048] f32, weight[32768,2048] f32, targets[4096] i32 -> scalar
//
//  Kc  convert_fp8  : f32 -> fp8 e4m3 copies (natural k order)
//  K0  target_logit : x_t[row] = softcap(h[row].w[tgt[row]]) fp32 (exact)
//  K1  gemm_mx      : 256x256 tile, BK=128, 8 waves, MX-scaled fp8 MFMA
//                     (unit scales -> numerically = e4m3 GEMM, 2x rate).
//                     R9 vs R8: i32x8 operands built via shufflevector
//                     (loads land directly in the 8-reg tuple) and A-frags
//                     loaded one-at-a-time inside the MFMA loop — kills the
//                     register spill (R8: 352 MB scratch writes).
//  K2  row_reduce   : sum column-block partials per row
//  K3  final_reduce : scalar loss

#define N_ROWS 4096
#define DIM    2048
#define VOCAB  32768
#define IGNORE_IDX (-100)

#define BM 256
#define BN 256
#define BK 128
#define NT (DIM / BK)            // 16 K-tiles
#define NCB (VOCAB / BN)         // 128 column blocks
#define ROW_TILES (N_ROWS / BM)  // 16

typedef short s16x8 __attribute__((ext_vector_type(8)));
typedef unsigned short u16x8 __attribute__((ext_vector_type(8)));
typedef float f32x4 __attribute__((ext_vector_type(4)));
typedef int   i32x4 __attribute__((ext_vector_type(4)));
typedef int   i32x8 __attribute__((ext_vector_type(8)));

#define AS3(p) ((__attribute__((address_space(3))) void*)(p))
#define AS1(p) ((const __attribute__((address_space(1))) void*)(p))

#define UNIT_SCALE 0x7F7F7F7F    // E8M0 127 = 2^0 in every byte

// 20*tanh(x/20) via hardware exp; clamp keeps exp finite for any input.
__device__ __forceinline__ float softcap(float x) {
    x = fminf(80.f, fmaxf(-80.f, x));
    float e = __expf(x * 0.1f);
    return 20.f * (e - 1.f) * __builtin_amdgcn_rcpf(e + 1.f);
}

// f32 -> bf16 RNE (fallback path only)
__device__ __forceinline__ unsigned short f2bf(float f) {
    union { float f; unsigned u; } v; v.f = f;
    unsigned r = v.u + 0x7FFFu + ((v.u >> 16) & 1u);
    return (unsigned short)(r >> 16);
}

// ---------------------------------------------------------------------------
// Kc: f32 -> fp8 e4m3, natural (linear) k order. One thread = 16 elems.
// ---------------------------------------------------------------------------
__global__ __launch_bounds__(256) void convert_fp8(
    const float* __restrict__ src, unsigned char* __restrict__ dst, int nchunk)
{
    int idx = blockIdx.x * 256 + threadIdx.x;
    int stride = gridDim.x * 256;
    for (int i = idx; i < nchunk; i += stride) {
        const float* p = src + (size_t)i * 16;
        float4 a0 = *(const float4*)(p);
        float4 a1 = *(const float4*)(p + 4);
        float4 b0 = *(const float4*)(p + 8);
        float4 b1 = *(const float4*)(p + 12);
        int w0 = __builtin_amdgcn_cvt_pk_fp8_f32(a0.x, a0.y, 0, false);
        w0     = __builtin_amdgcn_cvt_pk_fp8_f32(a0.z, a0.w, w0, true);
        int w1 = __builtin_amdgcn_cvt_pk_fp8_f32(a1.x, a1.y, 0, false);
        w1     = __builtin_amdgcn_cvt_pk_fp8_f32(a1.z, a1.w, w1, true);
        int w2 = __builtin_amdgcn_cvt_pk_fp8_f32(b0.x, b0.y, 0, false);
        w2     = __builtin_amdgcn_cvt_pk_fp8_f32(b0.z, b0.w, w2, true);
        int w3 = __builtin_amdgcn_cvt_pk_fp8_f32(b1.x, b1.y, 0, false);
        w3     = __builtin_amdgcn_cvt_pk_fp8_f32(b1.z, b1.w, w3, true);
        *(int4*)(dst + (size_t)i * 16) = make_int4(w0, w1, w2, w3);
    }
}

// ---------------------------------------------------------------------------
// K0: x_t[row] = softcap(dot(hidden[row], weight[tgt])) fp32. 1 wave/row.
// ---------------------------------------------------------------------------
__global__ __launch_bounds__(256) void target_logit(
    const float* __restrict__ hidden, const float* __restrict__ weight,
    const int* __restrict__ targets, float* __restrict__ xtbuf)
{
    int row  = blockIdx.x * 4 + (threadIdx.x >> 6);
    int lane = threadIdx.x & 63;
    if (row >= N_ROWS) return;
    int tgt = targets[row];
    if (tgt < 0 || tgt >= VOCAB) {
        if (lane == 0) xtbuf[row] = 0.f;
        return;
    }
    const float4* h4 = (const float4*)(hidden + (size_t)row * DIM);
    const float4* w4 = (const float4*)(weight + (size_t)tgt * DIM);
    float d = 0.f;
#pragma unroll
    for (int j = 0; j < DIM / 4 / 64; j++) {
        float4 a = h4[lane + 64 * j];
        float4 b = w4[lane + 64 * j];
        d += a.x * b.x + a.y * b.y + a.z * b.z + a.w * b.w;
    }
#pragma unroll
    for (int off = 1; off < 64; off <<= 1) d += __shfl_xor(d, off, 64);
    if (lane == 0) xtbuf[row] = softcap(d);
}

// ---------------------------------------------------------------------------
// K1: 256x256 8-wave MX-fp8 GEMM (K=128/MFMA), 2 windows/tile, fused partials.
//
// LDS (129+ KB): Abuf[2] @ {0,32K}, Bbuf[2] @ {64K,96K}, dummy @128K (1KB).
// Tile t reads buf t&1. Rows are 128 B = 8 x 16B slots;
//   phys slot = logical slot ^ (row&7)
// Readers XOR; stager inverse-permutes the global SOURCE, LDS dest linear.
// Per b128 the 64 lanes spread uniformly 8 words/bank (structural floor).
//
// Chunks = 64 rows, 1 global_load_lds per wave (8 rows each):
//   A chunks ci=0..3 = rows [64ci,64ci+64); same for B.
// Schedule: W0 (acc[0..3]): read B frags + A frags m-at-a-time; issue 2 =
//   (t+1, A ci1,ci3); 32 MFMA; vmcnt(8); barrier.  W1 (acc[4..7]): A frags;
//   issue 6 = (t+2, B ci0-3 + A ci0,ci2) into buf t&1 (reads retired in W0);
//   32 MFMA; vmcnt(8); barrier.  ct>=NT -> dummy (counts stay exact).
// ---------------------------------------------------------------------------
__device__ __forceinline__ void stage_mx(
    int isB, int ci, int ct, const unsigned char* Asrc, const unsigned char* Bsrc,
    unsigned char* smem, int w, int laneoff)
{
    const int kcol = (ct & (NT - 1)) * BK;
    const int row0 = ci * 64 + 8 * w;
    const int base = (isB ? 65536 : 0) + (ct & 1) * 32768;
    const int dest = (ct >= NT) ? 131072 : base + row0 * 128;
    const unsigned char* src = (isB ? Bsrc : Asrc) + (size_t)row0 * DIM + kcol + laneoff;
    __builtin_amdgcn_global_load_lds(AS1(src), AS3(smem + dest), 16, 0, 0);
}

// two ds_read_b128 -> one 8-reg tuple (no element-wise copies)
#define LDFRAG(buf, ro)                                                        \
    __builtin_shufflevector(*(const i32x4*)((buf) + (ro) + colx0),             \
                            *(const i32x4*)((buf) + (ro) + colx1),             \
                            0, 1, 2, 3, 4, 5, 6, 7)

__global__ __launch_bounds__(512, 2) void gemm_mx(
    const unsigned char* __restrict__ A, const unsigned char* __restrict__ B,
    float2* __restrict__ part)
{
    __shared__ unsigned char smem[131072 + 1024] __attribute__((aligned(16)));

    const int bid  = blockIdx.x;
    const int brow = bid & (ROW_TILES - 1);   // 16 consecutive blocks share B panel
    const int bcol = bid >> 4;
    const int t0   = threadIdx.x;
    const int lane = t0 & 63;
    const int w    = t0 >> 6;                 // 0..7
    const int wr   = w >> 2;                  // 0..1 (M)
    const int wc   = w & 3;                   // 0..3 (N)
    const int li   = lane & 15;
    const int g    = lane >> 4;               // 0..3 (k-group: k = g*32+[0,32))

    // swizzled byte offsets of the two 16B halves of this lane's fragment
    const int colx0 = (((2 * g)     ^ (li & 7)) << 4);
    const int colx1 = (((2 * g + 1) ^ (li & 7)) << 4);

    // staging source (inverse swizzle): lane l covers row_local l>>3,
    // phys slot l&7 -> logical slot (l&7)^(l>>3).
    const int laneoff = (lane >> 3) * DIM + (((lane & 7) ^ (lane >> 3)) << 4);

    const unsigned char* Asrc = A + (size_t)brow * BM * DIM;
    const unsigned char* Bsrc = B + (size_t)bcol * BN * DIM;

    f32x4 acc[8][4];
#pragma unroll
    for (int m = 0; m < 8; m++)
#pragma unroll
        for (int n = 0; n < 4; n++) acc[m][n] = (f32x4){0.f, 0.f, 0.f, 0.f};

    // ---- prologue: 14 instrs; vmcnt(8) confirms (0, B ci0-3 + A ci0,ci2) ----
    stage_mx(1, 0, 0, Asrc, Bsrc, smem, w, laneoff);
    stage_mx(1, 1, 0, Asrc, Bsrc, smem, w, laneoff);
    stage_mx(1, 2, 0, Asrc, Bsrc, smem, w, laneoff);
    stage_mx(1, 3, 0, Asrc, Bsrc, smem, w, laneoff);
    stage_mx(0, 0, 0, Asrc, Bsrc, smem, w, laneoff);
    stage_mx(0, 2, 0, Asrc, Bsrc, smem, w, laneoff);
    stage_mx(0, 1, 0, Asrc, Bsrc, smem, w, laneoff);
    stage_mx(0, 3, 0, Asrc, Bsrc, smem, w, laneoff);
    stage_mx(1, 0, 1, Asrc, Bsrc, smem, w, laneoff);
    stage_mx(1, 1, 1, Asrc, Bsrc, smem, w, laneoff);
    stage_mx(1, 2, 1, Asrc, Bsrc, smem, w, laneoff);
    stage_mx(1, 3, 1, Asrc, Bsrc, smem, w, laneoff);
    stage_mx(0, 0, 1, Asrc, Bsrc, smem, w, laneoff);
    stage_mx(0, 2, 1, Asrc, Bsrc, smem, w, laneoff);
    asm volatile("s_waitcnt vmcnt(8)" ::: "memory");
    __builtin_amdgcn_s_barrier();
    __builtin_amdgcn_sched_barrier(0);

    i32x8 bfr[4];

    for (int t = 0; t < NT; ++t) {
        const int b = t & 1;
        unsigned char* A_rd = smem + b * 32768;
        unsigned char* B_rd = smem + 65536 + b * 32768;

        // ---------------- window 0: acc[0..3] ----------------
        {
#pragma unroll
            for (int n = 0; n < 4; n++)
                bfr[n] = LDFRAG(B_rd, (wc * 64 + n * 16 + li) * 128);
            stage_mx(0, 1, t + 1, Asrc, Bsrc, smem, w, laneoff);
            stage_mx(0, 3, t + 1, Asrc, Bsrc, smem, w, laneoff);
            __builtin_amdgcn_s_setprio(1);
#pragma unroll
            for (int m = 0; m < 4; m++) {
                i32x8 afr = LDFRAG(A_rd, (wr * 128 + m * 16 + li) * 128);
#pragma unroll
                for (int n = 0; n < 4; n++)
                    acc[m][n] = __builtin_amdgcn_mfma_scale_f32_16x16x128_f8f6f4(
                        afr, bfr[n], acc[m][n],
                        0, 0, 0, UNIT_SCALE, 0, UNIT_SCALE);
            }
            __builtin_amdgcn_s_setprio(0);
            asm volatile("s_waitcnt vmcnt(8)" ::: "memory");
            __builtin_amdgcn_s_barrier();
            __builtin_amdgcn_sched_barrier(0);
        }
        // ---------------- window 1: acc[4..7] ----------------
        {
            stage_mx(1, 0, t + 2, Asrc, Bsrc, smem, w, laneoff);
            stage_mx(1, 1, t + 2, Asrc, Bsrc, smem, w, laneoff);
            stage_mx(1, 2, t + 2, Asrc, Bsrc, smem, w, laneoff);
            stage_mx(1, 3, t + 2, Asrc, Bsrc, smem, w, laneoff);
            stage_mx(0, 0, t + 2, Asrc, Bsrc, smem, w, laneoff);
            stage_mx(0, 2, t + 2, Asrc, Bsrc, smem, w, laneoff);
            __builtin_amdgcn_s_setprio(1);
#pragma unroll
            for (int m = 0; m < 4; m++) {
                i32x8 afr = LDFRAG(A_rd, (wr * 128 + 64 + m * 16 + li) * 128);
#pragma unroll
                for (int n = 0; n < 4; n++)
                    acc[m + 4][n] = __builtin_amdgcn_mfma_scale_f32_16x16x128_f8f6f4(
                        afr, bfr[n], acc[m + 4][n],
                        0, 0, 0, UNIT_SCALE, 0, UNIT_SCALE);
            }
            __builtin_amdgcn_s_setprio(0);
            asm volatile("s_waitcnt vmcnt(8)" ::: "memory");
            __builtin_amdgcn_s_barrier();
            __builtin_amdgcn_sched_barrier(0);
        }
    }

    // ---- epilogue: per-row (sum_exp, sum_logit) over 256 columns ----
    __syncthreads();   // full drain (also retires dummy wrap prefetches)
    float* red = (float*)smem;   // [8][128][2] f32 = 8 KB, aliases Abuf0
                                 // (last tile 15 reads buf1 @32K/@96K — safe)
#pragma unroll
    for (int m = 0; m < 8; m++) {
#pragma unroll
        for (int r = 0; r < 4; r++) {
            float s0 = softcap(acc[m][0][r]);
            float s1 = softcap(acc[m][1][r]);
            float s2 = softcap(acc[m][2][r]);
            float s3 = softcap(acc[m][3][r]);
            float se = __expf(s0) + __expf(s1) + __expf(s2) + __expf(s3);
            float st = s0 + s1 + s2 + s3;
#pragma unroll
            for (int off = 1; off < 16; off <<= 1) {
                se += __shfl_xor(se, off, 64);
                st += __shfl_xor(st, off, 64);
            }
            if (li == 0) {
                int rl = m * 16 + g * 4 + r;          // row within wave's 128
                int base = ((wr * 4 + wc) * 128 + rl) * 2;
                red[base + 0] = se;
                red[base + 1] = st;
            }
        }
    }
    __syncthreads();
    if (t0 < BM) {
        int r   = t0;
        int wr2 = r >> 7;
        int rr  = r & 127;
        float se = 0.f, st = 0.f;
#pragma unroll
        for (int q = 0; q < 4; q++) {
            int bq = ((wr2 * 4 + q) * 128 + rr) * 2;
            se += red[bq + 0];
            st += red[bq + 1];
        }
        part[(size_t)(brow * BM + r) * NCB + bcol] = make_float2(se, st);
    }
}

// ---------------------------------------------------------------------------
// K1 fallback (small ws): reg-staged f32->bf16, 128x128, BK=32.
// ---------------------------------------------------------------------------
__global__ __launch_bounds__(256) void gemm_partial_f32(
    const float* __restrict__ hidden, const float* __restrict__ weight,
    float2* __restrict__ part)
{
    __shared__ unsigned short sA[128 * 32];
    __shared__ unsigned short sB[128 * 32];
    __shared__ float red[4][64][2];

    const int bid  = blockIdx.x;
    const int brow = bid & 31;
    const int bcol = bid >> 5;
    const int t    = threadIdx.x;
    const int lane = t & 63;
    const int w    = t >> 6;
    const int wr   = w >> 1, wc = w & 1;

    const int srow = t >> 1;
    const int scol = (t & 1) * 16;
    const float* gA = hidden + (size_t)(brow * 128 + srow) * DIM + scol;
    const float* gB = weight + (size_t)(bcol * 128 + srow) * DIM + scol;
    unsigned short* wA = &sA[srow * 32 + scol];
    unsigned short* wB = &sB[srow * 32 + scol];

    f32x4 acc[4][4];
#pragma unroll
    for (int m = 0; m < 4; m++)
#pragma unroll
        for (int n = 0; n < 4; n++) acc[m][n] = (f32x4){0.f, 0.f, 0.f, 0.f};

    const unsigned short* pa = &sA[(wr * 64 + (lane & 15)) * 32 + (lane >> 4) * 8];
    const unsigned short* pb = &sB[(wc * 64 + (lane & 15)) * 32 + (lane >> 4) * 8];

    for (int k0 = 0; k0 < DIM; k0 += 32) {
        float4 a0 = *(const float4*)(gA + k0);
        float4 a1 = *(const float4*)(gA + k0 + 4);
        float4 a2 = *(const float4*)(gA + k0 + 8);
        float4 a3 = *(const float4*)(gA + k0 + 12);
        float4 b0 = *(const float4*)(gB + k0);
        float4 b1 = *(const float4*)(gB + k0 + 4);
        float4 b2 = *(const float4*)(gB + k0 + 8);
        float4 b3 = *(const float4*)(gB + k0 + 12);
        __syncthreads();
        u16x8 pa0 = { f2bf(a0.x), f2bf(a0.y), f2bf(a0.z), f2bf(a0.w),
                      f2bf(a1.x), f2bf(a1.y), f2bf(a1.z), f2bf(a1.w) };
        u16x8 pa1 = { f2bf(a2.x), f2bf(a2.y), f2bf(a2.z), f2bf(a2.w),
                      f2bf(a3.x), f2bf(a3.y), f2bf(a3.z), f2bf(a3.w) };
        u16x8 pb0 = { f2bf(b0.x), f2bf(b0.y), f2bf(b0.z), f2bf(b0.w),
                      f2bf(b1.x), f2bf(b1.y), f2bf(b1.z), f2bf(b1.w) };
        u16x8 pb1 = { f2bf(b2.x), f2bf(b2.y), f2bf(b2.z), f2bf(b2.w),
                      f2bf(b3.x), f2bf(b3.y), f2bf(b3.z), f2bf(b3.w) };
        *(u16x8*)wA = pa0;
        *(u16x8*)(wA + 8) = pa1;
        *(u16x8*)wB = pb0;
        *(u16x8*)(wB + 8) = pb1;
        __syncthreads();

        s16x8 afr[4], bfr[4];
#pragma unroll
        for (int m = 0; m < 4; m++) afr[m] = *(const s16x8*)(pa + m * 16 * 32);
#pragma unroll
        for (int n = 0; n < 4; n++) bfr[n] = *(const s16x8*)(pb + n * 16 * 32);
#pragma unroll
        for (int m = 0; m < 4; m++)
#pragma unroll
            for (int n = 0; n < 4; n++)
                acc[m][n] = __builtin_amdgcn_mfma_f32_16x16x32_bf16(
                    afr[m], bfr[n], acc[m][n], 0, 0, 0);
    }

    const int g  = lane >> 4;
    const int li = lane & 15;
#pragma unroll
    for (int m = 0; m < 4; m++) {
#pragma unroll
        for (int r = 0; r < 4; r++) {
            float s0 = softcap(acc[m][0][r]);
            float s1 = softcap(acc[m][1][r]);
            float s2 = softcap(acc[m][2][r]);
            float s3 = softcap(acc[m][3][r]);
            float se = __expf(s0) + __expf(s1) + __expf(s2) + __expf(s3);
            float st = s0 + s1 + s2 + s3;
#pragma unroll
            for (int off = 1; off < 16; off <<= 1) {
                se += __shfl_xor(se, off, 64);
                st += __shfl_xor(st, off, 64);
            }
            if (li == 0) {
                int rl = m * 16 + g * 4 + r;
                red[w][rl][0] = se;
                red[w][rl][1] = st;
            }
        }
    }
    __syncthreads();
    if (t < 128) {
        int r  = t;
        int wa = (r >> 6) * 2;
        int rr = r & 63;
        float se = red[wa][rr][0] + red[wa + 1][rr][0];
        float st = red[wa][rr][1] + red[wa + 1][rr][1];
        part[(size_t)(brow * 128 + r) * 256 + bcol] = make_float2(se, st);
    }
}

// ---------------------------------------------------------------------------
// K2: sum ncb column-block partials per row. 1 wave/row.
// ---------------------------------------------------------------------------
__global__ __launch_bounds__(256) void row_reduce(
    const float2* __restrict__ part, const int* __restrict__ targets,
    const float* __restrict__ xtbuf, float* __restrict__ rowbuf, int ncb)
{
    int row  = blockIdx.x * 4 + (threadIdx.x >> 6);
    int lane = threadIdx.x & 63;
    if (row >= N_ROWS) return;
    const float2* p = part + (size_t)row * ncb;
    float se = 0.f, st = 0.f;
    for (int q = lane; q < ncb; q += 64) {
        float2 u = p[q];
        se += u.x;
        st += u.y;
    }
#pragma unroll
    for (int off = 1; off < 64; off <<= 1) {
        se += __shfl_xor(se, off, 64);
        st += __shfl_xor(st, off, 64);
    }
    if (lane == 0) {
        float lse = logf(se);
        int   tgt = targets[row];
        float vf  = (tgt != IGNORE_IDX) ? 1.f : 0.f;
        float xt  = xtbuf[row];
        float nll = lse - xt;
        float smooth = lse - st * (1.f / (float)VOCAB);
        float rl = 0.9f * nll + 0.1f * smooth;
        rowbuf[row * 3 + 0] = rl * vf;
        rowbuf[row * 3 + 1] = lse * lse * vf;
        rowbuf[row * 3 + 2] = vf;
    }
}

// ---------------------------------------------------------------------------
// K3: deterministic final reduction -> scalar loss.
// ---------------------------------------------------------------------------
__global__ __launch_bounds__(256) void final_reduce(
    const float* __restrict__ rowbuf, float* __restrict__ out)
{
    __shared__ float sl[256], sz[256], sv[256];
    int t = threadIdx.x;
    float ls = 0.f, zs = 0.f, vs = 0.f;
    for (int r = t; r < N_ROWS; r += 256) {
        ls += rowbuf[r * 3 + 0];
        zs += rowbuf[r * 3 + 1];
        vs += rowbuf[r * 3 + 2];
    }
    sl[t] = ls; sz[t] = zs; sv[t] = vs;
    __syncthreads();
    for (int o = 128; o > 0; o >>= 1) {
        if (t < o) { sl[t] += sl[t + o]; sz[t] += sz[t + o]; sv[t] += sv[t + o]; }
        __syncthreads();
    }
    if (t == 0) {
        float nv = fmaxf(sv[0], 1.f);
        out[0] = sl[0] / nv + 1e-4f * (sz[0] / nv);
    }
}

// ---------------------------------------------------------------------------
extern "C" void kernel_launch(void* const* d_in, const int* in_sizes, int n_in,
                              void* d_out, int out_size, void* d_ws, size_t ws_size,
                              hipStream_t stream)
{
    const float* hidden  = (const float*)d_in[0];
    const float* weight  = (const float*)d_in[1];
    const int*   targets = (const int*)d_in[2];
    float*       out     = (float*)d_out;

    char* ws = (char*)d_ws;
    size_t off = 0;
    float2* part = (float2*)(ws + off);
    off += (size_t)N_ROWS * 256 * sizeof(float4);           // 16 MB slot (max layout)
    float* xtbuf = (float*)(ws + off);
    off += (size_t)N_ROWS * sizeof(float);
    float* rowbuf = (float*)(ws + off);
    off += (size_t)N_ROWS * 3 * sizeof(float);
    off = (off + 255) & ~(size_t)255;
    unsigned char* hid8 = (unsigned char*)(ws + off);
    off += (size_t)N_ROWS * DIM;                            // 8 MB
    unsigned char* wgt8 = (unsigned char*)(ws + off);
    off += (size_t)VOCAB * DIM;                             // 67 MB

    target_logit<<<N_ROWS / 4, 256, 0, stream>>>(hidden, weight, targets, xtbuf);

    if (ws_size >= off) {
        convert_fp8<<<2048, 256, 0, stream>>>(hidden, hid8, N_ROWS * (DIM / 16));
        convert_fp8<<<2048, 256, 0, stream>>>(weight, wgt8, VOCAB * (DIM / 16));
        gemm_mx<<<ROW_TILES * (VOCAB / BN), 512, 0, stream>>>(hid8, wgt8, part);
        row_reduce<<<N_ROWS / 4, 256, 0, stream>>>(part, targets, xtbuf, rowbuf, NCB);
    } else {
        gemm_partial_f32<<<32 * 256, 256, 0, stream>>>(hidden, weight, part);
        row_reduce<<<N_ROWS / 4, 256, 0, stream>>>(part, targets, xtbuf, rowbuf, 256);
    }

    final_reduce<<<1, 256, 0, stream>>>(rowbuf, out);
}